// Round 6
// baseline (464.567 us; speedup 1.0000x reference)
//
#include <hip/hip_runtime.h>
#include <cstddef>
#include <cstdint>

#define NN 50000
#define NE 600000
#define NB 391                    // buckets of 128 dst nodes

typedef __attribute__((ext_vector_type(8))) short bf16x8;
typedef __attribute__((ext_vector_type(4))) float f32x4;

#define SWZ(x) (((x) ^ ((x) >> 2)) & 3)

#define GLDS16(src, dst)                                                     \
    __builtin_amdgcn_global_load_lds(                                        \
        (const __attribute__((address_space(1))) void*)(src),                \
        (__attribute__((address_space(3))) void*)(dst), 16, 0, 0)

// raw barrier + counted waits (T3/T4). sched_barrier fences per rule #18.
#define SBAR() do { __builtin_amdgcn_sched_barrier(0);                        \
                    __builtin_amdgcn_s_barrier();                             \
                    __builtin_amdgcn_sched_barrier(0); } while (0)
#define WVM(N) do { asm volatile("s_waitcnt vmcnt(" #N ")" ::: "memory");     \
                    __builtin_amdgcn_sched_barrier(0); } while (0)
#define WLG()  do { asm volatile("s_waitcnt lgkmcnt(0)" ::: "memory");        \
                    __builtin_amdgcn_sched_barrier(0); } while (0)

__device__ __forceinline__ float bf2f(ushort u) {
    return __uint_as_float(((uint32_t)u) << 16);
}
__device__ __forceinline__ ushort f2bf(float f) {   // round-to-nearest-even
    uint32_t b = __float_as_uint(f);
    return (ushort)((b + 0x7FFF + ((b >> 16) & 1)) >> 16);
}

// ---------------------------------------------------------------- convert_weights + bhist (merged, independent)
__global__ __launch_bounds__(256)
void convbh_kernel(const float* __restrict__ f1W, const float* __restrict__ f2W,
                   const float* __restrict__ gW, const float* __restrict__ fgW,
                   const float* __restrict__ l1W, ushort* __restrict__ wt,
                   const int* __restrict__ dst, int* __restrict__ bcnt)
{
    if (blockIdx.x < 1312) {
        int i = blockIdx.x * 256 + threadIdx.x;          // 0 .. 335871
        if (i >= 335872) return;
        float v;
        if (i < 4096) {                                  // wf1
            int c = i >> 5, k = i & 31;
            v = f1W[k * 128 + c];
        } else if (i < 8192) {                           // wf2
            int j = i - 4096; int c = j >> 5, k = j & 31;
            v = f2W[k * 128 + c];
        } else if (i < 8192 + 98304) {                   // wg
            int j = i - 8192; int l = j >> 14, r = j & 16383;
            int c = r >> 7, k = r & 127;
            v = gW[l * 16384 + k * 128 + c];
        } else if (i < 8192 + 98304 + 196608) {          // wfg
            int j = i - (8192 + 98304); int l = j >> 15, r = j & 32767;
            int c = r >> 8, k = r & 255;
            v = fgW[l * 32768 + k * 128 + c];
        } else {                                         // wl1
            int j = i - (8192 + 98304 + 196608);
            int c = j >> 8, k = j & 255;
            v = l1W[k * 128 + c];
        }
        wt[i] = f2bf(v);
    } else {
        __shared__ int h[NB];
        int tx = threadIdx.x;
        for (int i = tx; i < NB; i += 256) h[i] = 0;
        __syncthreads();
        int e0 = (blockIdx.x - 1312) * 1024;
#pragma unroll
        for (int k = 0; k < 4; ++k) {
            int e = e0 + k * 256 + tx;
            if (e < NE) atomicAdd(&h[dst[e] >> 7], 1);
        }
        __syncthreads();
        for (int i = tx; i < NB; i += 256)
            if (h[i]) atomicAdd(&bcnt[i], h[i]);
    }
}

// ---------------------------------------------------------------- bscan
__global__ __launch_bounds__(512)
void bscan_kernel(const int* __restrict__ bcnt, int* __restrict__ bbase,
                  int* __restrict__ bcur)
{
    __shared__ int buf[512];
    int t = threadIdx.x;
    int v = (t < NB) ? bcnt[t] : 0;
    buf[t] = v;
    __syncthreads();
    for (int s = 1; s < 512; s <<= 1) {
        int u = (t >= s) ? buf[t - s] : 0;
        __syncthreads();
        buf[t] += u;
        __syncthreads();
    }
    if (t < NB) {
        int ex = buf[t] - v;
        bbase[t] = ex;
        bcur[t]  = ex;
    }
    if (t == 0) bbase[NB] = NE;
}

// ---------------------------------------------------------------- pass1
__global__ __launch_bounds__(256)
void pass1_kernel(const int* __restrict__ src, const int* __restrict__ dst,
                  const float* __restrict__ w, int* __restrict__ bcur,
                  unsigned int* __restrict__ stage_pk,
                  unsigned char* __restrict__ stage_dl)
{
    __shared__ int cnt[NB];
    __shared__ int gbase[NB];
    int tx = threadIdx.x;
    for (int i = tx; i < NB; i += 256) cnt[i] = 0;
    __syncthreads();
    int e0 = blockIdx.x * 1024;
    int myd[4], myrank[4];
    unsigned int mypk[4];
#pragma unroll
    for (int k = 0; k < 4; ++k) {
        int e = e0 + k * 256 + tx;
        if (e < NE) {
            int d = dst[e];
            myd[k]    = d;
            mypk[k]   = (unsigned int)src[e] | ((unsigned int)f2bf(w[e]) << 17);
            myrank[k] = atomicAdd(&cnt[d >> 7], 1);
        } else {
            myd[k] = -1;
        }
    }
    __syncthreads();
    for (int i = tx; i < NB; i += 256)
        gbase[i] = cnt[i] ? atomicAdd(&bcur[i], cnt[i]) : 0;
    __syncthreads();
#pragma unroll
    for (int k = 0; k < 4; ++k) {
        if (myd[k] >= 0) {
            int p = gbase[myd[k] >> 7] + myrank[k];
            stage_pk[p] = mypk[k];
            stage_dl[p] = (unsigned char)(myd[k] & 127);
        }
    }
}

// ---------------------------------------------------------------- pass2 + preproc (merged, independent)
__global__ __launch_bounds__(256)
void p2pre_kernel(const unsigned int* __restrict__ stage_pk,
                  const unsigned char* __restrict__ stage_dl,
                  const int* __restrict__ bbase,
                  unsigned int* __restrict__ esw, int* __restrict__ off,
                  const float* __restrict__ x, const float* __restrict__ preW,
                  const float* __restrict__ preb, ushort* __restrict__ h0b)
{
    if (blockIdx.x < NB) {
        __shared__ int h[128];
        __shared__ int lofs[128];
        int b    = blockIdx.x;
        int tx   = threadIdx.x;
        int base = bbase[b];
        int cnt  = bbase[b + 1] - base;
        if (tx < 128) h[tx] = 0;
        __syncthreads();
        for (int i = tx; i < cnt; i += 256)
            atomicAdd(&h[stage_dl[base + i]], 1);
        __syncthreads();
        if (tx == 0) {
            int run = 0;
            for (int i = 0; i < 128; ++i) { lofs[i] = run; run += h[i]; }
        }
        __syncthreads();
        int node0 = b * 128;
        if (tx < 128) {
            int n = node0 + tx;
            if (n < NN) off[n] = base + lofs[tx];
            h[tx] = 0;                       // reset for rank pass
        }
        if (b == NB - 1 && tx == 0) off[NN] = NE;
        __syncthreads();
        for (int i = tx; i < cnt; i += 256) {
            int d = stage_dl[base + i];
            int r = atomicAdd(&h[d], 1);
            esw[base + lofs[d] + r] = stage_pk[base + i];
        }
    } else {
        __shared__ float Wl[512];
        __shared__ float bl[32];
        int tx = threadIdx.x;
        Wl[tx]       = preW[tx];
        Wl[tx + 256] = preW[tx + 256];
        if (tx < 32) bl[tx] = preb[tx];
        __syncthreads();
        int n = (blockIdx.x - NB) * 256 + tx;
        if (n >= NN) return;
        float xr[16];
        const float4* xp = (const float4*)(x + (size_t)n * 16);
#pragma unroll
        for (int q = 0; q < 4; ++q) {
            float4 v = xp[q];
            xr[q*4+0]=v.x; xr[q*4+1]=v.y; xr[q*4+2]=v.z; xr[q*4+3]=v.w;
        }
        float acc[32];
#pragma unroll
        for (int c = 0; c < 32; ++c) acc[c] = bl[c];
#pragma unroll
        for (int k = 0; k < 16; ++k)
#pragma unroll
            for (int c = 0; c < 32; ++c)
                acc[c] = fmaf(xr[k], Wl[k*32+c], acc[c]);
        ushort4* op = (ushort4*)(h0b + (size_t)n * 32);
#pragma unroll
        for (int q = 0; q < 8; ++q) {
            ushort4 v;
            v.x = f2bf(fmaxf(acc[q*4+0], 0.f));
            v.y = f2bf(fmaxf(acc[q*4+1], 0.f));
            v.z = f2bf(fmaxf(acc[q*4+2], 0.f));
            v.w = f2bf(fmaxf(acc[q*4+3], 0.f));
            op[q] = v;
        }
    }
}

// ---------------------------------------------------------------- fc_in1 + fused layer0 (merged; both read h0b only)
__global__ __launch_bounds__(128)
void fc1f0_kernel(const ushort* __restrict__ h0b,
                  const ushort* __restrict__ wf1, const float* __restrict__ f1b,
                  ushort* __restrict__ nidb,
                  const ushort* __restrict__ wf2, const float* __restrict__ f2b,
                  const ushort* __restrict__ wg, ushort* __restrict__ hwb)
{
    __shared__ ushort Atile[64 * 32];
    __shared__ ushort Btile[128 * 32];
    __shared__ ushort Xt[64 * 128];
    const int tx   = threadIdx.x;
    const int wave = tx >> 6;
    const int lane = tx & 63;
    const int rs  = lane >> 2;
    const int chn = (lane & 3) ^ SWZ(rs);
    const int m    = lane & 15;
    const int quad = lane >> 4;
    const int slot = quad ^ SWZ(m);

    if (blockIdx.x < 782) {
        // ---- fc_in1 path (K=32) ----
        const int bm = blockIdx.x * 64;
        f32x4 acc0[8], acc1[8];
#pragma unroll
        for (int t = 0; t < 8; ++t) {
            acc0[t] = (f32x4){0.f, 0.f, 0.f, 0.f};
            acc1[t] = (f32x4){0.f, 0.f, 0.f, 0.f};
        }
#pragma unroll
        for (int i = 0; i < 2; ++i) {
            int seg = wave + 2 * i;
            int row = seg * 16 + rs;
            int ar  = bm + row; if (ar >= NN) ar = NN - 1;
            GLDS16(h0b + (size_t)ar * 32 + chn * 8, Atile + seg * 512);
        }
#pragma unroll
        for (int i = 0; i < 4; ++i) {
            int seg = wave + 2 * i;
            int col = seg * 16 + rs;
            GLDS16(wf1 + (size_t)col * 32 + chn * 8, Btile + seg * 512);
        }
        __syncthreads();
        bf16x8 af0 = *(const bf16x8*)(Atile + (wave * 32 + m) * 32 + slot * 8);
        bf16x8 af1 = *(const bf16x8*)(Atile + (wave * 32 + 16 + m) * 32 + slot * 8);
#pragma unroll
        for (int t = 0; t < 8; ++t) {
            bf16x8 bfr = *(const bf16x8*)(Btile + (t * 16 + m) * 32 + slot * 8);
            acc0[t] = __builtin_amdgcn_mfma_f32_16x16x32_bf16(af0, bfr, acc0[t], 0, 0, 0);
            acc1[t] = __builtin_amdgcn_mfma_f32_16x16x32_bf16(af1, bfr, acc1[t], 0, 0, 0);
        }
        __syncthreads();
#pragma unroll
        for (int half = 0; half < 2; ++half) {
            const int orow0 = bm + wave * 32 + half * 16 + quad * 4;
#pragma unroll
            for (int t = 0; t < 8; ++t) {
                int col = t * 16 + m;
                float bb = f1b[col];
                f32x4 a = half ? acc1[t] : acc0[t];
#pragma unroll
                for (int r = 0; r < 4; ++r) {
                    int row = orow0 + r;
                    if (row < NN)
                        nidb[(size_t)row * 128 + col] = f2bf(fmaxf(a[r] + bb, 0.f));
                }
            }
        }
    } else {
        // ---- fused layer0 path: X = relu(h0b@wf2+f2b); hwb = X@wg0 ----
        const int bm = (blockIdx.x - 782) * 64;
        f32x4 acc0[8], acc1[8];
#pragma unroll
        for (int t = 0; t < 8; ++t) {
            acc0[t] = (f32x4){0.f, 0.f, 0.f, 0.f};
            acc1[t] = (f32x4){0.f, 0.f, 0.f, 0.f};
        }
#pragma unroll
        for (int i = 0; i < 2; ++i) {
            int seg = wave + 2 * i;
            int row = seg * 16 + rs;
            int ar  = bm + row; if (ar >= NN) ar = NN - 1;
            GLDS16(h0b + (size_t)ar * 32 + chn * 8, Atile + seg * 512);
        }
#pragma unroll
        for (int i = 0; i < 4; ++i) {
            int seg = wave + 2 * i;
            int col = seg * 16 + rs;
            GLDS16(wf2 + (size_t)col * 32 + chn * 8, Btile + seg * 512);
        }
        __syncthreads();
        {
            bf16x8 af0 = *(const bf16x8*)(Atile + (wave * 32 + m) * 32 + slot * 8);
            bf16x8 af1 = *(const bf16x8*)(Atile + (wave * 32 + 16 + m) * 32 + slot * 8);
#pragma unroll
            for (int t = 0; t < 8; ++t) {
                bf16x8 bfr = *(const bf16x8*)(Btile + (t * 16 + m) * 32 + slot * 8);
                acc0[t] = __builtin_amdgcn_mfma_f32_16x16x32_bf16(af0, bfr, acc0[t], 0, 0, 0);
                acc1[t] = __builtin_amdgcn_mfma_f32_16x16x32_bf16(af1, bfr, acc1[t], 0, 0, 0);
            }
        }
        __syncthreads();
#pragma unroll
        for (int half = 0; half < 2; ++half) {
            int rbase = wave * 32 + half * 16 + quad * 4;
#pragma unroll
            for (int t = 0; t < 8; ++t) {
                int col = t * 16 + m;
                float bb = f2b[col];
                int c32 = col >> 5, within = col & 7, ks = (col >> 3) & 3;
                f32x4 a = half ? acc1[t] : acc0[t];
#pragma unroll
                for (int r = 0; r < 4; ++r) {
                    int row = rbase + r;
                    int pos = ks ^ SWZ(row & 15);
                    Xt[row * 128 + c32 * 32 + pos * 8 + within] =
                        f2bf(fmaxf(a[r] + bb, 0.f));
                }
            }
        }
#pragma unroll
        for (int t = 0; t < 8; ++t) {
            acc0[t] = (f32x4){0.f, 0.f, 0.f, 0.f};
            acc1[t] = (f32x4){0.f, 0.f, 0.f, 0.f};
        }
        __syncthreads();
        for (int c32 = 0; c32 < 4; ++c32) {
            int kk = c32 * 32;
#pragma unroll
            for (int i = 0; i < 4; ++i) {
                int seg = wave + 2 * i;
                int col = seg * 16 + rs;
                GLDS16(wg + (size_t)col * 128 + kk + chn * 8, Btile + seg * 512);
            }
            __syncthreads();
            bf16x8 af0 = *(const bf16x8*)(Xt + (wave * 32 + m) * 128 + kk + slot * 8);
            bf16x8 af1 = *(const bf16x8*)(Xt + (wave * 32 + 16 + m) * 128 + kk + slot * 8);
#pragma unroll
            for (int t = 0; t < 8; ++t) {
                bf16x8 bfr = *(const bf16x8*)(Btile + (t * 16 + m) * 32 + slot * 8);
                acc0[t] = __builtin_amdgcn_mfma_f32_16x16x32_bf16(af0, bfr, acc0[t], 0, 0, 0);
                acc1[t] = __builtin_amdgcn_mfma_f32_16x16x32_bf16(af1, bfr, acc1[t], 0, 0, 0);
            }
            __syncthreads();
        }
#pragma unroll
        for (int half = 0; half < 2; ++half) {
            const int orow0 = bm + wave * 32 + half * 16 + quad * 4;
#pragma unroll
            for (int t = 0; t < 8; ++t) {
                int col = t * 16 + m;
                f32x4 a = half ? acc1[t] : acc0[t];
#pragma unroll
                for (int r = 0; r < 4; ++r) {
                    int row = orow0 + r;
                    if (row < NN)
                        hwb[(size_t)row * 128 + col] = f2bf(a[r]);
                }
            }
        }
    }
}

// ---------------------------------------------------------------- fused gather + GEMM (64-row, 8 waves)
// Pipelined gather (2-deep rv batches) + double-buffered staging with counted
// vmcnt + raw barriers (stage(c+1) loads stay in flight across barriers).
__global__ __launch_bounds__(512)
void gemm_gather(const ushort* __restrict__ hw,
                 const unsigned int* __restrict__ esw,
                 const int* __restrict__ off,
                 const float* __restrict__ gbias,
                 const ushort* __restrict__ nid,
                 const ushort* __restrict__ Wt,     // [col 128][k 256]
                 const float* __restrict__ bias,
                 const ushort* __restrict__ Wg,     // [col 128][k 128]
                 ushort* __restrict__ out_hw, int nrows)
{
    __shared__ ushort Atile[2][64 * 32];
    __shared__ ushort Btile[2][128 * 32];
    __shared__ ushort AggXt[64 * 128];
    const int tx   = threadIdx.x;
    const int wave = tx >> 6;          // 0..7
    const int lane = tx & 63;
    const int bm   = blockIdx.x * 64;
    const int g    = wave >> 1;
    const int h    = wave & 1;
    const int rs   = lane >> 2;
    const int chn  = (lane & 3) ^ SWZ(rs);
    const int m    = lane & 15;
    const int quad = lane >> 4;
    const int slot = quad ^ SWZ(m);

    int aar = bm + wave * 16 + rs; if (aar >= nrows) aar = nrows - 1;  // waves 0-3

    auto stA = [&](int koff, int buf) {
        if (wave < 4)
            GLDS16(nid + (size_t)aar * 128 + koff + chn * 8, Atile[buf] + wave * 512);
    };
    auto stB = [&](const ushort* W, int ldk, int koff, int buf) {
        int col = wave * 16 + rs;
        GLDS16(W + (size_t)col * ldk + koff + chn * 8, Btile[buf] + wave * 512);
    };

    f32x4 acc[4];
#pragma unroll
    for (int t = 0; t < 4; ++t) acc[t] = (f32x4){0.f, 0.f, 0.f, 0.f};

    auto mmA = [&](int buf) {
        bf16x8 af = *(const bf16x8*)(Atile[buf] + (g * 16 + m) * 32 + slot * 8);
#pragma unroll
        for (int t = 0; t < 4; ++t) {
            bf16x8 bfr = *(const bf16x8*)(Btile[buf] + (h * 64 + t * 16 + m) * 32 + slot * 8);
            acc[t] = __builtin_amdgcn_mfma_f32_16x16x32_bf16(af, bfr, acc[t], 0, 0, 0);
        }
    };
    auto mmX = [&](int kb, int buf) {
        const int row = g * 16 + m, rx = (row & 1) << 5;
        bf16x8 af = *(const bf16x8*)(AggXt + row * 128 + ((kb * 32 + slot * 8) ^ rx));
#pragma unroll
        for (int t = 0; t < 4; ++t) {
            bf16x8 bfr = *(const bf16x8*)(Btile[buf] + (h * 64 + t * 16 + m) * 32 + slot * 8);
            acc[t] = __builtin_amdgcn_mfma_f32_16x16x32_bf16(af, bfr, acc[t], 0, 0, 0);
        }
    };

    // ---- entry prefetch: chunk 0 (lands during gather) ----
    stA(0, 0); stB(Wt, 256, 0, 0);

    // ---- gather: 8 dst nodes per wave, 2-deep pipelined ----
    {
        const int n0   = bm + wave * 8;
        const int nend = n0 + 8;
        int n    = n0;
        const int base = off[n0 < NN ? n0 : NN];
        const int end  = off[nend < NN ? nend : NN];
        int nb = (n < NN) ? off[n + 1] : 0x7fffffff;
        const ushort* hp = hw + lane * 2;
        const float g0 = gbias[lane * 2], g1 = gbias[lane * 2 + 1];
        float a0 = 0.f, a1 = 0.f;
        const int c32g = lane >> 4;
        const int ksg  = (lane >> 2) & 3;
        const int wth  = (2 * lane) & 7;

        auto flushTo = [&](int e) {
            while (e == nb) {
                int row = n - bm;
                unsigned int o = (unsigned int)f2bf(fmaxf(a0 + g0, 0.f)) |
                                 ((unsigned int)f2bf(fmaxf(a1 + g1, 0.f)) << 16);
                int pos = ksg ^ SWZ(row & 15);
                *(unsigned int*)(AggXt + row * 128 +
                    ((c32g * 32 + pos * 8 + wth) ^ ((row & 1) << 5))) = o;
                a0 = 0.f; a1 = 0.f;
                ++n;
                nb = (n < nend && n < NN) ? off[n + 1] : 0x7fffffff;
            }
        };

        const int total = end - base;
        const int lim   = total < 128 ? total : 128;
        int pk0 = (base + lane < end)      ? (int)esw[base + lane]      : 0;
        int pk1 = (base + 64 + lane < end) ? (int)esw[base + 64 + lane] : 0;

        unsigned int rvA[16], rvB[16];
        auto issueB16 = [&](int b, unsigned int* rv) {
            int pkw = (b < 4) ? pk0 : pk1;
            int jo  = (b & 3) * 16;
#pragma unroll
            for (int k = 0; k < 16; ++k) {
                int pp = __builtin_amdgcn_readlane(pkw, jo + k);
                rv[k] = *(const unsigned int*)(hp + (size_t)(pp & 0x1FFFF) * 128);
            }
        };
        auto procB16 = [&](int b, const unsigned int* rv) {
            int pkw = (b < 4) ? pk0 : pk1;
            int jo  = (b & 3) * 16;
            int eb  = base + b * 16;
#pragma unroll
            for (int k = 0; k < 16; ++k) {
                int e = eb + k;
                if (e >= end) break;
                flushTo(e);
                int pp = __builtin_amdgcn_readlane(pkw, jo + k);
                float w = bf2f((ushort)((unsigned int)pp >> 17));
                a0 = fmaf(bf2f((ushort)(rv[k] & 0xffffu)), w, a0);
                a1 = fmaf(bf2f((ushort)(rv[k] >> 16)), w, a1);
            }
        };

        if (lim > 0) {
            issueB16(0, rvA);
            int b = 0;
            for (;;) {
                if ((b + 1) * 16 < lim) issueB16(b + 1, rvB);
                procB16(b, rvA);
                ++b; if (b * 16 >= lim) break;
                if ((b + 1) * 16 < lim) issueB16(b + 1, rvA);
                procB16(b, rvB);
                ++b; if (b * 16 >= lim) break;
            }
        }
        // remainder (>128 edges per wave — rare): unpipelined
        for (int chunk = base + 128; chunk < end; chunk += 64) {
            int idx = chunk + lane;
            int pk = (idx < end) ? (int)esw[idx] : 0;
            int cnt = end - chunk; if (cnt > 64) cnt = 64;
            int cnt16 = (cnt + 15) & ~15;
            for (int j = 0; j < cnt16; j += 16) {
                int pp[16];
                unsigned int rv[16];
#pragma unroll
                for (int k = 0; k < 16; ++k)
                    pp[k] = __builtin_amdgcn_readlane(pk, j + k);
#pragma unroll
                for (int k = 0; k < 16; ++k)
                    rv[k] = *(const unsigned int*)(hp + (size_t)(pp[k] & 0x1FFFF) * 128);
#pragma unroll
                for (int k = 0; k < 16; ++k) {
                    int e = chunk + j + k;
                    if (e >= end) break;
                    flushTo(e);
                    float w = bf2f((ushort)((unsigned int)pp[k] >> 17));
                    a0 = fmaf(bf2f((ushort)(rv[k] & 0xffff)), w, a0);
                    a1 = fmaf(bf2f((ushort)(rv[k] >> 16)),    w, a1);
                }
            }
        }
        while (n < nend) {                            // flush remaining rows
            int row = n - bm;
            unsigned int o = (unsigned int)f2bf(fmaxf(a0 + g0, 0.f)) |
                             ((unsigned int)f2bf(fmaxf(a1 + g1, 0.f)) << 16);
            int pos = ksg ^ SWZ(row & 15);
            *(unsigned int*)(AggXt + row * 128 +
                ((c32g * 32 + pos * 8 + wth) ^ ((row & 1) << 5))) = o;
            a0 = 0.f; a1 = 0.f;
            ++n;
        }
    }

    __syncthreads();   // full drain once: gather + chunk-0 staging all visible

    // ---- stage 1: X = relu(nid@top + Agg@bot + bias), K=256, counted-vmcnt pipeline ----
    stA(32, 1); stB(Wt, 256, 32, 1);
    if (wave < 4) { WVM(2); } else { WVM(1); }
    SBAR(); mmA(0); WLG(); SBAR();
    stA(64, 0); stB(Wt, 256, 64, 0);
    if (wave < 4) { WVM(2); } else { WVM(1); }
    SBAR(); mmA(1); WLG(); SBAR();
    stA(96, 1); stB(Wt, 256, 96, 1);
    if (wave < 4) { WVM(2); } else { WVM(1); }
    SBAR(); mmA(0); WLG(); SBAR();
    stB(Wt, 256, 128, 0); WVM(1); SBAR(); mmA(1);    WLG(); SBAR();
    stB(Wt, 256, 160, 1); WVM(1); SBAR(); mmX(0, 0); WLG(); SBAR();
    stB(Wt, 256, 192, 0); WVM(1); SBAR(); mmX(1, 1); WLG(); SBAR();
    stB(Wt, 256, 224, 1); WVM(1); SBAR(); mmX(2, 0); WLG(); SBAR();
                          WVM(0); SBAR(); mmX(3, 1); WLG(); SBAR();

    // ---- juncture: prefetch Wg chunk0, epilogue-1 -> Xt (= AggXt) ----
    stB(Wg, 128, 0, 0);
    {
        int rbase = g * 16 + quad * 4;
#pragma unroll
        for (int t = 0; t < 4; ++t) {
            int col = h * 64 + t * 16 + m;
            float bb = bias[col];
            int c32 = col >> 5, within = col & 7, ks = (col >> 3) & 3;
#pragma unroll
            for (int r = 0; r < 4; ++r) {
                int row = rbase + r;
                int pos = ks ^ SWZ(row & 15);
                AggXt[row * 128 + ((c32 * 32 + pos * 8 + within) ^ ((row & 1) << 5))] =
                    f2bf(fmaxf(acc[t][r] + bb, 0.f));
            }
        }
    }
#pragma unroll
    for (int t = 0; t < 4; ++t) acc[t] = (f32x4){0.f, 0.f, 0.f, 0.f};
    WLG(); SBAR();

    // ---- stage 2: out_hw = X @ Wg^T (K=128) ----
    stB(Wg, 128, 32, 1); WVM(1); SBAR(); mmX(0, 0); WLG(); SBAR();
    stB(Wg, 128, 64, 0); WVM(1); SBAR(); mmX(1, 1); WLG(); SBAR();
    stB(Wg, 128, 96, 1); WVM(1); SBAR(); mmX(2, 0); WLG(); SBAR();
                         WVM(0); SBAR(); mmX(3, 1);

    // ---- epilogue 2 ----
    {
        const int orow0 = bm + g * 16 + quad * 4;
#pragma unroll
        for (int t = 0; t < 4; ++t) {
            int col = h * 64 + t * 16 + m;
#pragma unroll
            for (int r = 0; r < 4; ++r) {
                int row = orow0 + r;
                if (row < nrows)
                    out_hw[(size_t)row * 128 + col] = f2bf(acc[t][r]);
            }
        }
    }
}

// ---------------------------------------------------------------- last fused (gather + 2 GEMMs + head, 8 waves)
__global__ __launch_bounds__(512)
void gemm_last(const ushort* __restrict__ hw,
               const unsigned int* __restrict__ esw,
               const int* __restrict__ off,
               const float* __restrict__ gbias,
               const ushort* __restrict__ nid,
               const ushort* __restrict__ Wt, const float* __restrict__ bias5,
               const ushort* __restrict__ Wl1, const float* __restrict__ l1b,
               const float* __restrict__ l2W, const float* __restrict__ l2b,
               float* __restrict__ out, int nrows)
{
    __shared__ ushort Atile[2][64 * 32];
    __shared__ ushort Btile[2][128 * 32];
    __shared__ ushort AggXt[64 * 128];
    const int tx   = threadIdx.x;
    const int wave = tx >> 6;
    const int lane = tx & 63;
    const int bm   = blockIdx.x * 64;
    const int g    = wave >> 1;
    const int h    = wave & 1;
    const int rs   = lane >> 2;
    const int chn  = (lane & 3) ^ SWZ(rs);
    const int m    = lane & 15;
    const int quad = lane >> 4;
    const int slot = quad ^ SWZ(m);

    int aar = bm + wave * 16 + rs; if (aar >= nrows) aar = nrows - 1;

    auto stA = [&](int koff, int buf) {
        if (wave < 4)
            GLDS16(nid + (size_t)aar * 128 + koff + chn * 8, Atile[buf] + wave * 512);
    };
    auto stB = [&](const ushort* W, int ldk, int koff, int buf) {
        int col = wave * 16 + rs;
        GLDS16(W + (size_t)col * ldk + koff + chn * 8, Btile[buf] + wave * 512);
    };

    f32x4 acc[4];
#pragma unroll
    for (int t = 0; t < 4; ++t) acc[t] = (f32x4){0.f, 0.f, 0.f, 0.f};

    auto mmA = [&](int buf) {
        bf16x8 af = *(const bf16x8*)(Atile[buf] + (g * 16 + m) * 32 + slot * 8);
#pragma unroll
        for (int t = 0; t < 4; ++t) {
            bf16x8 bfr = *(const bf16x8*)(Btile[buf] + (h * 64 + t * 16 + m) * 32 + slot * 8);
            acc[t] = __builtin_amdgcn_mfma_f32_16x16x32_bf16(af, bfr, acc[t], 0, 0, 0);
        }
    };
    auto mmX = [&](int kb, int buf) {
        const int row = g * 16 + m, rx = (row & 1) << 5;
        bf16x8 af = *(const bf16x8*)(AggXt + row * 128 + ((kb * 32 + slot * 8) ^ rx));
#pragma unroll
        for (int t = 0; t < 4; ++t) {
            bf16x8 bfr = *(const bf16x8*)(Btile[buf] + (h * 64 + t * 16 + m) * 32 + slot * 8);
            acc[t] = __builtin_amdgcn_mfma_f32_16x16x32_bf16(af, bfr, acc[t], 0, 0, 0);
        }
    };

    // ---- entry prefetch ----
    stA(0, 0); stB(Wt, 256, 0, 0);

    // ---- gather (pipelined, identical to gemm_gather) ----
    {
        const int n0   = bm + wave * 8;
        const int nend = n0 + 8;
        int n    = n0;
        const int base = off[n0 < NN ? n0 : NN];
        const int end  = off[nend < NN ? nend : NN];
        int nb = (n < NN) ? off[n + 1] : 0x7fffffff;
        const ushort* hp = hw + lane * 2;
        const float g0 = gbias[lane * 2], g1 = gbias[lane * 2 + 1];
        float a0 = 0.f, a1 = 0.f;
        const int c32g = lane >> 4;
        const int ksg  = (lane >> 2) & 3;
        const int wth  = (2 * lane) & 7;

        auto flushTo = [&](int e) {
            while (e == nb) {
                int row = n - bm;
                unsigned int o = (unsigned int)f2bf(fmaxf(a0 + g0, 0.f)) |
                                 ((unsigned int)f2bf(fmaxf(a1 + g1, 0.f)) << 16);
                int pos = ksg ^ SWZ(row & 15);
                *(unsigned int*)(AggXt + row * 128 +
                    ((c32g * 32 + pos * 8 + wth) ^ ((row & 1) << 5))) = o;
                a0 = 0.f; a1 = 0.f;
                ++n;
                nb = (n < nend && n < NN) ? off[n + 1] : 0x7fffffff;
            }
        };

        const int total = end - base;
        const int lim   = total < 128 ? total : 128;
        int pk0 = (base + lane < end)      ? (int)esw[base + lane]      : 0;
        int pk1 = (base + 64 + lane < end) ? (int)esw[base + 64 + lane] : 0;

        unsigned int rvA[16], rvB[16];
        auto issueB16 = [&](int b, unsigned int* rv) {
            int pkw = (b < 4) ? pk0 : pk1;
            int jo  = (b & 3) * 16;
#pragma unroll
            for (int k = 0; k < 16; ++k) {
                int pp = __builtin_amdgcn_readlane(pkw, jo + k);
                rv[k] = *(const unsigned int*)(hp + (size_t)(pp & 0x1FFFF) * 128);
            }
        };
        auto procB16 = [&](int b, const unsigned int* rv) {
            int pkw = (b < 4) ? pk0 : pk1;
            int jo  = (b & 3) * 16;
            int eb  = base + b * 16;
#pragma unroll
            for (int k = 0; k < 16; ++k) {
                int e = eb + k;
                if (e >= end) break;
                flushTo(e);
                int pp = __builtin_amdgcn_readlane(pkw, jo + k);
                float w = bf2f((ushort)((unsigned int)pp >> 17));
                a0 = fmaf(bf2f((ushort)(rv[k] & 0xffffu)), w, a0);
                a1 = fmaf(bf2f((ushort)(rv[k] >> 16)), w, a1);
            }
        };

        if (lim > 0) {
            issueB16(0, rvA);
            int b = 0;
            for (;;) {
                if ((b + 1) * 16 < lim) issueB16(b + 1, rvB);
                procB16(b, rvA);
                ++b; if (b * 16 >= lim) break;
                if ((b + 1) * 16 < lim) issueB16(b + 1, rvA);
                procB16(b, rvB);
                ++b; if (b * 16 >= lim) break;
            }
        }
        for (int chunk = base + 128; chunk < end; chunk += 64) {
            int idx = chunk + lane;
            int pk = (idx < end) ? (int)esw[idx] : 0;
            int cnt = end - chunk; if (cnt > 64) cnt = 64;
            int cnt16 = (cnt + 15) & ~15;
            for (int j = 0; j < cnt16; j += 16) {
                int pp[16];
                unsigned int rv[16];
#pragma unroll
                for (int k = 0; k < 16; ++k)
                    pp[k] = __builtin_amdgcn_readlane(pk, j + k);
#pragma unroll
                for (int k = 0; k < 16; ++k)
                    rv[k] = *(const unsigned int*)(hp + (size_t)(pp[k] & 0x1FFFF) * 128);
#pragma unroll
                for (int k = 0; k < 16; ++k) {
                    int e = chunk + j + k;
                    if (e >= end) break;
                    flushTo(e);
                    float w = bf2f((ushort)((unsigned int)pp[k] >> 17));
                    a0 = fmaf(bf2f((ushort)(rv[k] & 0xffff)), w, a0);
                    a1 = fmaf(bf2f((ushort)(rv[k] >> 16)),    w, a1);
                }
            }
        }
        while (n < nend) {
            int row = n - bm;
            unsigned int o = (unsigned int)f2bf(fmaxf(a0 + g0, 0.f)) |
                             ((unsigned int)f2bf(fmaxf(a1 + g1, 0.f)) << 16);
            int pos = ksg ^ SWZ(row & 15);
            *(unsigned int*)(AggXt + row * 128 +
                ((c32g * 32 + pos * 8 + wth) ^ ((row & 1) << 5))) = o;
            a0 = 0.f; a1 = 0.f;
            ++n;
        }
    }

    __syncthreads();

    // ---- stage 1: X = relu(nid@top + Agg@bot + b5), K=256 ----
    stA(32, 1); stB(Wt, 256, 32, 1);
    if (wave < 4) { WVM(2); } else { WVM(1); }
    SBAR(); mmA(0); WLG(); SBAR();
    stA(64, 0); stB(Wt, 256, 64, 0);
    if (wave < 4) { WVM(2); } else { WVM(1); }
    SBAR(); mmA(1); WLG(); SBAR();
    stA(96, 1); stB(Wt, 256, 96, 1);
    if (wave < 4) { WVM(2); } else { WVM(1); }
    SBAR(); mmA(0); WLG(); SBAR();
    stB(Wt, 256, 128, 0); WVM(1); SBAR(); mmA(1);    WLG(); SBAR();
    stB(Wt, 256, 160, 1); WVM(1); SBAR(); mmX(0, 0); WLG(); SBAR();
    stB(Wt, 256, 192, 0); WVM(1); SBAR(); mmX(1, 1); WLG(); SBAR();
    stB(Wt, 256, 224, 1); WVM(1); SBAR(); mmX(2, 0); WLG(); SBAR();
                          WVM(0); SBAR(); mmX(3, 1); WLG(); SBAR();

    // ---- juncture: prefetch stage-2 chunk0 (A + Wl1), epilogue-1 -> Xt ----
    stA(0, 0); stB(Wl1, 256, 0, 0);
    {
        int rbase = g * 16 + quad * 4;
#pragma unroll
        for (int t = 0; t < 4; ++t) {
            int col = h * 64 + t * 16 + m;
            float bb = bias5[col];
            int c32 = col >> 5, within = col & 7, ks = (col >> 3) & 3;
#pragma unroll
            for (int r = 0; r < 4; ++r) {
                int row = rbase + r;
                int pos = ks ^ SWZ(row & 15);
                AggXt[row * 128 + ((c32 * 32 + pos * 8 + within) ^ ((row & 1) << 5))] =
                    f2bf(fmaxf(acc[t][r] + bb, 0.f));
            }
        }
    }
#pragma unroll
    for (int t = 0; t < 4; ++t) acc[t] = (f32x4){0.f, 0.f, 0.f, 0.f};
    WLG(); SBAR();

    // ---- stage 2: HH = nid@l1t + X@l1b, K=256 ----
    stA(32, 1); stB(Wl1, 256, 32, 1);
    if (wave < 4) { WVM(2); } else { WVM(1); }
    SBAR(); mmA(0); WLG(); SBAR();
    stA(64, 0); stB(Wl1, 256, 64, 0);
    if (wave < 4) { WVM(2); } else { WVM(1); }
    SBAR(); mmA(1); WLG(); SBAR();
    stA(96, 1); stB(Wl1, 256, 96, 1);
    if (wave < 4) { WVM(2); } else { WVM(1); }
    SBAR(); mmA(0); WLG(); SBAR();
    stB(Wl1, 256, 128, 0); WVM(1); SBAR(); mmA(1);    WLG(); SBAR();
    stB(Wl1, 256, 160, 1); WVM(1); SBAR(); mmX(0, 0); WLG(); SBAR();
    stB(Wl1, 256, 192, 0); WVM(1); SBAR(); mmX(1, 1); WLG(); SBAR();
    stB(Wl1, 256, 224, 1); WVM(1); SBAR(); mmX(2, 0); WLG(); SBAR();
                           WVM(0); SBAR(); mmX(3, 1);

    // ---- epilogue: relu(HH+l1b) @ l2W, pair-reduce, sigmoid ----
    float bb[4];
#pragma unroll
    for (int t = 0; t < 4; ++t) bb[t] = l1b[h * 64 + t * 16 + m];
    float pr0[4], pr1[4];
#pragma unroll
    for (int r = 0; r < 4; ++r) {
        float p0 = 0.f, p1 = 0.f;
#pragma unroll
        for (int t = 0; t < 4; ++t) {
            int col = h * 64 + t * 16 + m;
            float v = fmaxf(acc[t][r] + bb[t], 0.f);
            p0 = fmaf(v, l2W[col * 2 + 0], p0);
            p1 = fmaf(v, l2W[col * 2 + 1], p1);
        }
#pragma unroll
        for (int mask = 1; mask < 16; mask <<= 1) {
            p0 += __shfl_xor(p0, mask);
            p1 += __shfl_xor(p1, mask);
        }
        pr0[r] = p0; pr1[r] = p1;
    }
    float* pbuf = (float*)Atile;          // Atile dead (last read: stage-2 mmA)
    if (h == 1 && m == 0) {
#pragma unroll
        for (int r = 0; r < 4; ++r) {
            int lrow = g * 16 + quad * 4 + r;
            pbuf[lrow * 2 + 0] = pr0[r];
            pbuf[lrow * 2 + 1] = pr1[r];
        }
    }
    __syncthreads();
    if (h == 0 && m == 0) {
        float b20 = l2b[0], b21 = l2b[1];
#pragma unroll
        for (int r = 0; r < 4; ++r) {
            int lrow = g * 16 + quad * 4 + r;
            int row = bm + lrow;
            if (row < nrows) {
                float p0 = pr0[r] + pbuf[lrow * 2 + 0] + b20;
                float p1 = pr1[r] + pbuf[lrow * 2 + 1] + b21;
                out[(size_t)row * 2 + 0] = 1.f / (1.f + __expf(-p0));
                out[(size_t)row * 2 + 1] = 1.f / (1.f + __expf(-p1));
            }
        }
    }
}

// ---------------------------------------------------------------- launch
extern "C" void kernel_launch(void* const* d_in, const int* in_sizes, int n_in,
                              void* d_out, int out_size, void* d_ws, size_t ws_size,
                              hipStream_t stream)
{
    const float* x    = (const float*)d_in[0];
    const int*   esrc = (const int*)  d_in[1];
    const int*   edst = (const int*)  d_in[2];
    const float* ew   = (const float*)d_in[3];
    const float* preW = (const float*)d_in[4];
    const float* preb = (const float*)d_in[5];
    const float* f1W  = (const float*)d_in[6];
    const float* f1b  = (const float*)d_in[7];
    const float* f2W  = (const float*)d_in[8];
    const float* f2b  = (const float*)d_in[9];
    const float* gW   = (const float*)d_in[10];
    const float* gb   = (const float*)d_in[11];
    const float* fgW  = (const float*)d_in[12];
    const float* fgb  = (const float*)d_in[13];
    const float* l1W  = (const float*)d_in[14];
    const float* l1b  = (const float*)d_in[15];
    const float* l2W  = (const float*)d_in[16];
    const float* l2b  = (const float*)d_in[17];
    float* out = (float*)d_out;

    ushort* wt   = (ushort*)d_ws;
    ushort* wf1  = wt;                          //   4096
    ushort* wf2  = wf1 + 4096;                  //   4096
    ushort* wg   = wf2 + 4096;                  //  98304
    ushort* wfg  = wg  + 98304;                 // 196608
    ushort* wl1  = wfg + 196608;                //  32768
    ushort* h0b  = wl1 + 32768;                 // N*32
    ushort* nidb = h0b  + (size_t)NN * 32;      // N*128
    ushort* hwb  = nidb + (size_t)NN * 128;     // N*128 row-major (ping)
    ushort* hwb2 = hwb  + (size_t)NN * 128;     // N*128 row-major (pong)
    ushort* endu = hwb2 + (size_t)NN * 128;
    unsigned int* esw      = (unsigned int*)(((uintptr_t)endu + 15) & ~(uintptr_t)15);
    unsigned int* stage_pk = esw + NE;
    int*          bcnt     = (int*)(stage_pk + NE);   // NB
    int*          bbase    = bcnt + NB + 1;           // NB+1
    int*          bcur     = bbase + NB + 1;          // NB
    int*          off      = bcur + NB + 1;           // NN+1
    unsigned char* stage_dl = (unsigned char*)(off + NN + 2);  // NE bytes

    const int gblocks = (NN + 63) / 64;         // 782
    const int eblocks = (NE + 1023) / 1024;     // 586

    // ---- CSR build + preproc + weight conversion (merged where independent) ----
    hipMemsetAsync(bcnt, 0, (size_t)NB * sizeof(int), stream);
    convbh_kernel<<<1312 + eblocks, 256, 0, stream>>>(f1W, f2W, gW, fgW, l1W, wt,
                                                      edst, bcnt);
    bscan_kernel<<<1, 512, 0, stream>>>(bcnt, bbase, bcur);
    pass1_kernel<<<eblocks, 256, 0, stream>>>(esrc, edst, ew, bcur, stage_pk, stage_dl);
    p2pre_kernel<<<NB + (NN + 255) / 256, 256, 0, stream>>>(stage_pk, stage_dl, bbase,
                                                            esw, off, x, preW, preb, h0b);

    // ---- network ----
    fc1f0_kernel<<<2 * gblocks, 128, 0, stream>>>(h0b, wf1, f1b, nidb,
                                                  wf2, f2b, wg, hwb);
    ushort* cur = hwb;
    ushort* nxt = hwb2;
    for (int l = 0; l < 5; ++l) {
        gemm_gather<<<gblocks, 512, 0, stream>>>(cur, esw, off,
                                                 gb + (size_t)l * 128, nidb,
                                                 wfg + (size_t)l * 32768,
                                                 fgb + (size_t)l * 128,
                                                 wg + (size_t)(l + 1) * 16384,
                                                 nxt, NN);
        ushort* tmp = cur; cur = nxt; nxt = tmp;
    }
    gemm_last<<<gblocks, 512, 0, stream>>>(cur, esw, off,
                                           gb + (size_t)5 * 128, nidb,
                                           wfg + (size_t)5 * 32768,
                                           fgb + (size_t)5 * 128,
                                           wl1, l1b, l2W, l2b, out, NN);
}

// Round 7
// 415.144 us; speedup vs baseline: 1.1191x; 1.1191x over previous
//
#include <hip/hip_runtime.h>
#include <cstddef>
#include <cstdint>

#define NN 50000
#define NE 600000
#define NB 391                    // buckets of 128 dst nodes

typedef __attribute__((ext_vector_type(8))) short bf16x8;
typedef __attribute__((ext_vector_type(4))) float f32x4;

#define SWZ(x) (((x) ^ ((x) >> 2)) & 3)

#define GLDS16(src, dst)                                                     \
    __builtin_amdgcn_global_load_lds(                                        \
        (const __attribute__((address_space(1))) void*)(src),                \
        (__attribute__((address_space(3))) void*)(dst), 16, 0, 0)

__device__ __forceinline__ float bf2f(ushort u) {
    return __uint_as_float(((uint32_t)u) << 16);
}
__device__ __forceinline__ ushort f2bf(float f) {   // round-to-nearest-even
    uint32_t b = __float_as_uint(f);
    return (ushort)((b + 0x7FFF + ((b >> 16) & 1)) >> 16);
}

// ---------------------------------------------------------------- convert_weights + bhist (merged, independent)
__global__ __launch_bounds__(256)
void convbh_kernel(const float* __restrict__ f1W, const float* __restrict__ f2W,
                   const float* __restrict__ gW, const float* __restrict__ fgW,
                   const float* __restrict__ l1W, ushort* __restrict__ wt,
                   const int* __restrict__ dst, int* __restrict__ bcnt)
{
    if (blockIdx.x < 1312) {
        int i = blockIdx.x * 256 + threadIdx.x;          // 0 .. 335871
        if (i >= 335872) return;
        float v;
        if (i < 4096) {                                  // wf1
            int c = i >> 5, k = i & 31;
            v = f1W[k * 128 + c];
        } else if (i < 8192) {                           // wf2
            int j = i - 4096; int c = j >> 5, k = j & 31;
            v = f2W[k * 128 + c];
        } else if (i < 8192 + 98304) {                   // wg
            int j = i - 8192; int l = j >> 14, r = j & 16383;
            int c = r >> 7, k = r & 127;
            v = gW[l * 16384 + k * 128 + c];
        } else if (i < 8192 + 98304 + 196608) {          // wfg
            int j = i - (8192 + 98304); int l = j >> 15, r = j & 32767;
            int c = r >> 8, k = r & 255;
            v = fgW[l * 32768 + k * 128 + c];
        } else {                                         // wl1
            int j = i - (8192 + 98304 + 196608);
            int c = j >> 8, k = j & 255;
            v = l1W[k * 128 + c];
        }
        wt[i] = f2bf(v);
    } else {
        __shared__ int h[NB];
        int tx = threadIdx.x;
        for (int i = tx; i < NB; i += 256) h[i] = 0;
        __syncthreads();
        int e0 = (blockIdx.x - 1312) * 1024;
#pragma unroll
        for (int k = 0; k < 4; ++k) {
            int e = e0 + k * 256 + tx;
            if (e < NE) atomicAdd(&h[dst[e] >> 7], 1);
        }
        __syncthreads();
        for (int i = tx; i < NB; i += 256)
            if (h[i]) atomicAdd(&bcnt[i], h[i]);
    }
}

// ---------------------------------------------------------------- bscan
__global__ __launch_bounds__(512)
void bscan_kernel(const int* __restrict__ bcnt, int* __restrict__ bbase,
                  int* __restrict__ bcur)
{
    __shared__ int buf[512];
    int t = threadIdx.x;
    int v = (t < NB) ? bcnt[t] : 0;
    buf[t] = v;
    __syncthreads();
    for (int s = 1; s < 512; s <<= 1) {
        int u = (t >= s) ? buf[t - s] : 0;
        __syncthreads();
        buf[t] += u;
        __syncthreads();
    }
    if (t < NB) {
        int ex = buf[t] - v;
        bbase[t] = ex;
        bcur[t]  = ex;
    }
    if (t == 0) bbase[NB] = NE;
}

// ---------------------------------------------------------------- pass1
__global__ __launch_bounds__(256)
void pass1_kernel(const int* __restrict__ src, const int* __restrict__ dst,
                  const float* __restrict__ w, int* __restrict__ bcur,
                  unsigned int* __restrict__ stage_pk,
                  unsigned char* __restrict__ stage_dl)
{
    __shared__ int cnt[NB];
    __shared__ int gbase[NB];
    int tx = threadIdx.x;
    for (int i = tx; i < NB; i += 256) cnt[i] = 0;
    __syncthreads();
    int e0 = blockIdx.x * 1024;
    int myd[4], myrank[4];
    unsigned int mypk[4];
#pragma unroll
    for (int k = 0; k < 4; ++k) {
        int e = e0 + k * 256 + tx;
        if (e < NE) {
            int d = dst[e];
            myd[k]    = d;
            mypk[k]   = (unsigned int)src[e] | ((unsigned int)f2bf(w[e]) << 17);
            myrank[k] = atomicAdd(&cnt[d >> 7], 1);
        } else {
            myd[k] = -1;
        }
    }
    __syncthreads();
    for (int i = tx; i < NB; i += 256)
        gbase[i] = cnt[i] ? atomicAdd(&bcur[i], cnt[i]) : 0;
    __syncthreads();
#pragma unroll
    for (int k = 0; k < 4; ++k) {
        if (myd[k] >= 0) {
            int p = gbase[myd[k] >> 7] + myrank[k];
            stage_pk[p] = mypk[k];
            stage_dl[p] = (unsigned char)(myd[k] & 127);
        }
    }
}

// ---------------------------------------------------------------- pass2 + preproc (merged, independent)
__global__ __launch_bounds__(256)
void p2pre_kernel(const unsigned int* __restrict__ stage_pk,
                  const unsigned char* __restrict__ stage_dl,
                  const int* __restrict__ bbase,
                  unsigned int* __restrict__ esw, int* __restrict__ off,
                  const float* __restrict__ x, const float* __restrict__ preW,
                  const float* __restrict__ preb, ushort* __restrict__ h0b)
{
    if (blockIdx.x < NB) {
        __shared__ int h[128];
        __shared__ int lofs[128];
        int b    = blockIdx.x;
        int tx   = threadIdx.x;
        int base = bbase[b];
        int cnt  = bbase[b + 1] - base;
        if (tx < 128) h[tx] = 0;
        __syncthreads();
        for (int i = tx; i < cnt; i += 256)
            atomicAdd(&h[stage_dl[base + i]], 1);
        __syncthreads();
        if (tx == 0) {
            int run = 0;
            for (int i = 0; i < 128; ++i) { lofs[i] = run; run += h[i]; }
        }
        __syncthreads();
        int node0 = b * 128;
        if (tx < 128) {
            int n = node0 + tx;
            if (n < NN) off[n] = base + lofs[tx];
            h[tx] = 0;                       // reset for rank pass
        }
        if (b == NB - 1 && tx == 0) off[NN] = NE;
        __syncthreads();
        for (int i = tx; i < cnt; i += 256) {
            int d = stage_dl[base + i];
            int r = atomicAdd(&h[d], 1);
            esw[base + lofs[d] + r] = stage_pk[base + i];
        }
    } else {
        __shared__ float Wl[512];
        __shared__ float bl[32];
        int tx = threadIdx.x;
        Wl[tx]       = preW[tx];
        Wl[tx + 256] = preW[tx + 256];
        if (tx < 32) bl[tx] = preb[tx];
        __syncthreads();
        int n = (blockIdx.x - NB) * 256 + tx;
        if (n >= NN) return;
        float xr[16];
        const float4* xp = (const float4*)(x + (size_t)n * 16);
#pragma unroll
        for (int q = 0; q < 4; ++q) {
            float4 v = xp[q];
            xr[q*4+0]=v.x; xr[q*4+1]=v.y; xr[q*4+2]=v.z; xr[q*4+3]=v.w;
        }
        float acc[32];
#pragma unroll
        for (int c = 0; c < 32; ++c) acc[c] = bl[c];
#pragma unroll
        for (int k = 0; k < 16; ++k)
#pragma unroll
            for (int c = 0; c < 32; ++c)
                acc[c] = fmaf(xr[k], Wl[k*32+c], acc[c]);
        ushort4* op = (ushort4*)(h0b + (size_t)n * 32);
#pragma unroll
        for (int q = 0; q < 8; ++q) {
            ushort4 v;
            v.x = f2bf(fmaxf(acc[q*4+0], 0.f));
            v.y = f2bf(fmaxf(acc[q*4+1], 0.f));
            v.z = f2bf(fmaxf(acc[q*4+2], 0.f));
            v.w = f2bf(fmaxf(acc[q*4+3], 0.f));
            op[q] = v;
        }
    }
}

// ---------------------------------------------------------------- fc_in1 + fused layer0 (merged; both read h0b only)
__global__ __launch_bounds__(128)
void fc1f0_kernel(const ushort* __restrict__ h0b,
                  const ushort* __restrict__ wf1, const float* __restrict__ f1b,
                  ushort* __restrict__ nidb,
                  const ushort* __restrict__ wf2, const float* __restrict__ f2b,
                  const ushort* __restrict__ wg, ushort* __restrict__ hwb)
{
    __shared__ ushort Atile[64 * 32];
    __shared__ ushort Btile[128 * 32];
    __shared__ ushort Xt[64 * 128];
    const int tx   = threadIdx.x;
    const int wave = tx >> 6;
    const int lane = tx & 63;
    const int rs  = lane >> 2;
    const int chn = (lane & 3) ^ SWZ(rs);
    const int m    = lane & 15;
    const int quad = lane >> 4;
    const int slot = quad ^ SWZ(m);

    if (blockIdx.x < 782) {
        // ---- fc_in1 path (K=32) ----
        const int bm = blockIdx.x * 64;
        f32x4 acc0[8], acc1[8];
#pragma unroll
        for (int t = 0; t < 8; ++t) {
            acc0[t] = (f32x4){0.f, 0.f, 0.f, 0.f};
            acc1[t] = (f32x4){0.f, 0.f, 0.f, 0.f};
        }
#pragma unroll
        for (int i = 0; i < 2; ++i) {
            int seg = wave + 2 * i;
            int row = seg * 16 + rs;
            int ar  = bm + row; if (ar >= NN) ar = NN - 1;
            GLDS16(h0b + (size_t)ar * 32 + chn * 8, Atile + seg * 512);
        }
#pragma unroll
        for (int i = 0; i < 4; ++i) {
            int seg = wave + 2 * i;
            int col = seg * 16 + rs;
            GLDS16(wf1 + (size_t)col * 32 + chn * 8, Btile + seg * 512);
        }
        __syncthreads();
        bf16x8 af0 = *(const bf16x8*)(Atile + (wave * 32 + m) * 32 + slot * 8);
        bf16x8 af1 = *(const bf16x8*)(Atile + (wave * 32 + 16 + m) * 32 + slot * 8);
#pragma unroll
        for (int t = 0; t < 8; ++t) {
            bf16x8 bfr = *(const bf16x8*)(Btile + (t * 16 + m) * 32 + slot * 8);
            acc0[t] = __builtin_amdgcn_mfma_f32_16x16x32_bf16(af0, bfr, acc0[t], 0, 0, 0);
            acc1[t] = __builtin_amdgcn_mfma_f32_16x16x32_bf16(af1, bfr, acc1[t], 0, 0, 0);
        }
        __syncthreads();
#pragma unroll
        for (int half = 0; half < 2; ++half) {
            const int orow0 = bm + wave * 32 + half * 16 + quad * 4;
#pragma unroll
            for (int t = 0; t < 8; ++t) {
                int col = t * 16 + m;
                float bb = f1b[col];
                f32x4 a = half ? acc1[t] : acc0[t];
#pragma unroll
                for (int r = 0; r < 4; ++r) {
                    int row = orow0 + r;
                    if (row < NN)
                        nidb[(size_t)row * 128 + col] = f2bf(fmaxf(a[r] + bb, 0.f));
                }
            }
        }
    } else {
        // ---- fused layer0 path: X = relu(h0b@wf2+f2b); hwb = X@wg0 ----
        const int bm = (blockIdx.x - 782) * 64;
        f32x4 acc0[8], acc1[8];
#pragma unroll
        for (int t = 0; t < 8; ++t) {
            acc0[t] = (f32x4){0.f, 0.f, 0.f, 0.f};
            acc1[t] = (f32x4){0.f, 0.f, 0.f, 0.f};
        }
#pragma unroll
        for (int i = 0; i < 2; ++i) {
            int seg = wave + 2 * i;
            int row = seg * 16 + rs;
            int ar  = bm + row; if (ar >= NN) ar = NN - 1;
            GLDS16(h0b + (size_t)ar * 32 + chn * 8, Atile + seg * 512);
        }
#pragma unroll
        for (int i = 0; i < 4; ++i) {
            int seg = wave + 2 * i;
            int col = seg * 16 + rs;
            GLDS16(wf2 + (size_t)col * 32 + chn * 8, Btile + seg * 512);
        }
        __syncthreads();
        {
            bf16x8 af0 = *(const bf16x8*)(Atile + (wave * 32 + m) * 32 + slot * 8);
            bf16x8 af1 = *(const bf16x8*)(Atile + (wave * 32 + 16 + m) * 32 + slot * 8);
#pragma unroll
            for (int t = 0; t < 8; ++t) {
                bf16x8 bfr = *(const bf16x8*)(Btile + (t * 16 + m) * 32 + slot * 8);
                acc0[t] = __builtin_amdgcn_mfma_f32_16x16x32_bf16(af0, bfr, acc0[t], 0, 0, 0);
                acc1[t] = __builtin_amdgcn_mfma_f32_16x16x32_bf16(af1, bfr, acc1[t], 0, 0, 0);
            }
        }
        __syncthreads();
#pragma unroll
        for (int half = 0; half < 2; ++half) {
            int rbase = wave * 32 + half * 16 + quad * 4;
#pragma unroll
            for (int t = 0; t < 8; ++t) {
                int col = t * 16 + m;
                float bb = f2b[col];
                int c32 = col >> 5, within = col & 7, ks = (col >> 3) & 3;
                f32x4 a = half ? acc1[t] : acc0[t];
#pragma unroll
                for (int r = 0; r < 4; ++r) {
                    int row = rbase + r;
                    int pos = ks ^ SWZ(row & 15);
                    Xt[row * 128 + c32 * 32 + pos * 8 + within] =
                        f2bf(fmaxf(a[r] + bb, 0.f));
                }
            }
        }
#pragma unroll
        for (int t = 0; t < 8; ++t) {
            acc0[t] = (f32x4){0.f, 0.f, 0.f, 0.f};
            acc1[t] = (f32x4){0.f, 0.f, 0.f, 0.f};
        }
        __syncthreads();
        for (int c32 = 0; c32 < 4; ++c32) {
            int kk = c32 * 32;
#pragma unroll
            for (int i = 0; i < 4; ++i) {
                int seg = wave + 2 * i;
                int col = seg * 16 + rs;
                GLDS16(wg + (size_t)col * 128 + kk + chn * 8, Btile + seg * 512);
            }
            __syncthreads();
            bf16x8 af0 = *(const bf16x8*)(Xt + (wave * 32 + m) * 128 + kk + slot * 8);
            bf16x8 af1 = *(const bf16x8*)(Xt + (wave * 32 + 16 + m) * 128 + kk + slot * 8);
#pragma unroll
            for (int t = 0; t < 8; ++t) {
                bf16x8 bfr = *(const bf16x8*)(Btile + (t * 16 + m) * 32 + slot * 8);
                acc0[t] = __builtin_amdgcn_mfma_f32_16x16x32_bf16(af0, bfr, acc0[t], 0, 0, 0);
                acc1[t] = __builtin_amdgcn_mfma_f32_16x16x32_bf16(af1, bfr, acc1[t], 0, 0, 0);
            }
            __syncthreads();
        }
#pragma unroll
        for (int half = 0; half < 2; ++half) {
            const int orow0 = bm + wave * 32 + half * 16 + quad * 4;
#pragma unroll
            for (int t = 0; t < 8; ++t) {
                int col = t * 16 + m;
                f32x4 a = half ? acc1[t] : acc0[t];
#pragma unroll
                for (int r = 0; r < 4; ++r) {
                    int row = orow0 + r;
                    if (row < NN)
                        hwb[(size_t)row * 128 + col] = f2bf(a[r]);
                }
            }
        }
    }
}

// ---------------------------------------------------------------- fused gather + GEMM (32-row, 4 waves)
// Round-2 structure retiled: wave w gathers 8 nodes (rows w*8..w*8+7) into AggXt;
// GEMM wave-pair g=w>>1 (0..1) owns rows g*16..+15, col-half h=w&1 owns cols h*64..+63.
// 1563 blocks -> ~8 independent blocks/CU; barriers lock only 4 waves.
__global__ __launch_bounds__(256)
void gemm_gather(const ushort* __restrict__ hw,
                 const unsigned int* __restrict__ esw,
                 const int* __restrict__ off,
                 const float* __restrict__ gbias,
                 const ushort* __restrict__ nid,
                 const ushort* __restrict__ Wt,     // [col 128][k 256]
                 const float* __restrict__ bias,
                 const ushort* __restrict__ Wg,     // [col 128][k 128]
                 ushort* __restrict__ out_hw, int nrows)
{
    __shared__ ushort Atile[32 * 32];
    __shared__ ushort Btile[128 * 32];
    __shared__ ushort AggXt[32 * 128];
    const int tx   = threadIdx.x;
    const int wave = tx >> 6;          // 0..3
    const int lane = tx & 63;
    const int bm   = blockIdx.x * 32;
    const int g    = wave >> 1;        // row-group 0..1
    const int h    = wave & 1;         // col-half
    const int rs   = lane >> 2;
    const int chn  = (lane & 3) ^ SWZ(rs);
    const int m    = lane & 15;
    const int quad = lane >> 4;
    const int slot = quad ^ SWZ(m);

    // prefetch stage-1 chunk0 (lands during gather)
    if (wave < 2) {
        int ar = bm + wave * 16 + rs; if (ar >= nrows) ar = nrows - 1;
        GLDS16(nid + (size_t)ar * 128 + chn * 8, Atile + wave * 512);
    }
#pragma unroll
    for (int i = 0; i < 2; ++i) {
        int seg = wave + 4 * i;
        int col = seg * 16 + rs;
        GLDS16(Wt + (size_t)col * 256 + chn * 8, Btile + seg * 512);
    }

    // ---- gather: 8 dst nodes per wave -> AggXt rows ----
    {
        const int n0   = bm + wave * 8;
        const int nend = n0 + 8;
        int n    = n0;
        const int base = off[n0 < NN ? n0 : NN];
        const int end  = off[nend < NN ? nend : NN];
        int nb = (n < NN) ? off[n + 1] : 0x7fffffff;
        const ushort* hp = hw + lane * 2;
        const float g0 = gbias[lane * 2], g1 = gbias[lane * 2 + 1];
        float a0 = 0.f, a1 = 0.f;
        const int c32g = lane >> 4;
        const int ksg  = (lane >> 2) & 3;
        const int wth  = (2 * lane) & 7;
        for (int chunk = base; chunk < end; chunk += 64) {
            int idx = chunk + lane;
            int pk = (idx < end) ? (int)esw[idx] : 0;
            int cnt = end - chunk; if (cnt > 64) cnt = 64;
            int cnt16 = (cnt + 15) & ~15;
            for (int j = 0; j < cnt16; j += 16) {
                int pp[16];
                unsigned int rv[16];
#pragma unroll
                for (int k = 0; k < 16; ++k)
                    pp[k] = __builtin_amdgcn_readlane(pk, j + k);
#pragma unroll
                for (int k = 0; k < 16; ++k)
                    rv[k] = *(const unsigned int*)(hp + (size_t)(pp[k] & 0x1FFFF) * 128);
#pragma unroll
                for (int k = 0; k < 16; ++k) {
                    int e = chunk + j + k;
                    while (e == nb) {                 // node boundary: flush node n
                        int row = n - bm;
                        unsigned int o = (unsigned int)f2bf(fmaxf(a0 + g0, 0.f)) |
                                         ((unsigned int)f2bf(fmaxf(a1 + g1, 0.f)) << 16);
                        int pos = ksg ^ SWZ(row & 15);
                        *(unsigned int*)(AggXt + row * 128 +
                            ((c32g * 32 + pos * 8 + wth) ^ ((row & 1) << 5))) = o;
                        a0 = 0.f; a1 = 0.f;
                        ++n;
                        nb = (n < nend && n < NN) ? off[n + 1] : 0x7fffffff;
                    }
                    float w = bf2f((ushort)((unsigned int)pp[k] >> 17));
                    a0 = fmaf(bf2f((ushort)(rv[k] & 0xffff)), w, a0);
                    a1 = fmaf(bf2f((ushort)(rv[k] >> 16)),    w, a1);
                }
            }
        }
        while (n < nend) {                            // flush remaining rows
            int row = n - bm;
            unsigned int o = (unsigned int)f2bf(fmaxf(a0 + g0, 0.f)) |
                             ((unsigned int)f2bf(fmaxf(a1 + g1, 0.f)) << 16);
            int pos = ksg ^ SWZ(row & 15);
            *(unsigned int*)(AggXt + row * 128 +
                ((c32g * 32 + pos * 8 + wth) ^ ((row & 1) << 5))) = o;
            a0 = 0.f; a1 = 0.f;
            ++n;
        }
    }

    f32x4 acc[4];
#pragma unroll
    for (int t = 0; t < 4; ++t) acc[t] = (f32x4){0.f, 0.f, 0.f, 0.f};

    // ---- stage 1: X = relu(nid@top + Agg@bot + bias), K=256 ----
    for (int c8 = 0; c8 < 8; ++c8) {
        int kk = c8 * 32;
        if (c8 > 0) {
            if (c8 < 4 && wave < 2) {
                int ar = bm + wave * 16 + rs; if (ar >= nrows) ar = nrows - 1;
                GLDS16(nid + (size_t)ar * 128 + kk + chn * 8, Atile + wave * 512);
            }
#pragma unroll
            for (int i = 0; i < 2; ++i) {
                int seg = wave + 4 * i;
                int col = seg * 16 + rs;
                GLDS16(Wt + (size_t)col * 256 + kk + chn * 8, Btile + seg * 512);
            }
        }
        __syncthreads();
        bf16x8 af;
        if (c8 < 4) {
            af = *(const bf16x8*)(Atile + (g * 16 + m) * 32 + slot * 8);
        } else {
            int row = g * 16 + m;
            af = *(const bf16x8*)(AggXt + row * 128 +
                 (((c8 - 4) * 32 + slot * 8) ^ ((row & 1) << 5)));
        }
#pragma unroll
        for (int t = 0; t < 4; ++t) {
            bf16x8 bfr = *(const bf16x8*)(Btile + (h * 64 + t * 16 + m) * 32 + slot * 8);
            acc[t] = __builtin_amdgcn_mfma_f32_16x16x32_bf16(af, bfr, acc[t], 0, 0, 0);
        }
        __syncthreads();
    }

    // prefetch stage-2 chunk0 B (Btile free after final stage-1 barrier)
#pragma unroll
    for (int i = 0; i < 2; ++i) {
        int seg = wave + 4 * i;
        int col = seg * 16 + rs;
        GLDS16(Wg + (size_t)col * 128 + chn * 8, Btile + seg * 512);
    }

    // ---- epilogue 1: bias+relu -> Xt (= AggXt), zero acc ----
    {
        int rbase = g * 16 + quad * 4;
#pragma unroll
        for (int t = 0; t < 4; ++t) {
            int col = h * 64 + t * 16 + m;
            float bb = bias[col];
            int c32 = col >> 5, within = col & 7, ks = (col >> 3) & 3;
#pragma unroll
            for (int r = 0; r < 4; ++r) {
                int row = rbase + r;
                int pos = ks ^ SWZ(row & 15);
                AggXt[row * 128 + ((c32 * 32 + pos * 8 + within) ^ ((row & 1) << 5))] =
                    f2bf(fmaxf(acc[t][r] + bb, 0.f));
            }
        }
    }
#pragma unroll
    for (int t = 0; t < 4; ++t) acc[t] = (f32x4){0.f, 0.f, 0.f, 0.f};
    __syncthreads();

    // ---- stage 2: out_hw = X @ Wg^T (K=128) ----
    for (int c4 = 0; c4 < 4; ++c4) {
        int kk = c4 * 32;
        if (c4 > 0) {
#pragma unroll
            for (int i = 0; i < 2; ++i) {
                int seg = wave + 4 * i;
                int col = seg * 16 + rs;
                GLDS16(Wg + (size_t)col * 128 + kk + chn * 8, Btile + seg * 512);
            }
            __syncthreads();
        }
        int row = g * 16 + m;
        bf16x8 af = *(const bf16x8*)(AggXt + row * 128 +
                    ((kk + slot * 8) ^ ((row & 1) << 5)));
#pragma unroll
        for (int t = 0; t < 4; ++t) {
            bf16x8 bfr = *(const bf16x8*)(Btile + (h * 64 + t * 16 + m) * 32 + slot * 8);
            acc[t] = __builtin_amdgcn_mfma_f32_16x16x32_bf16(af, bfr, acc[t], 0, 0, 0);
        }
        __syncthreads();
    }

    // ---- epilogue 2 ----
    {
        const int orow0 = bm + g * 16 + quad * 4;
#pragma unroll
        for (int t = 0; t < 4; ++t) {
            int col = h * 64 + t * 16 + m;
#pragma unroll
            for (int r = 0; r < 4; ++r) {
                int row = orow0 + r;
                if (row < nrows)
                    out_hw[(size_t)row * 128 + col] = f2bf(acc[t][r]);
            }
        }
    }
}

// ---------------------------------------------------------------- last fused (gather + 2 GEMMs + head, 4 waves, 32-row)
__global__ __launch_bounds__(256)
void gemm_last(const ushort* __restrict__ hw,
               const unsigned int* __restrict__ esw,
               const int* __restrict__ off,
               const float* __restrict__ gbias,
               const ushort* __restrict__ nid,
               const ushort* __restrict__ Wt, const float* __restrict__ bias5,
               const ushort* __restrict__ Wl1, const float* __restrict__ l1b,
               const float* __restrict__ l2W, const float* __restrict__ l2b,
               float* __restrict__ out, int nrows)
{
    __shared__ ushort Atile[32 * 32];
    __shared__ ushort Btile[128 * 32];
    __shared__ ushort AggXt[32 * 128];
    __shared__ float  w2s[256];
    __shared__ float  pbuf[32][2];
    const int tx   = threadIdx.x;
    const int wave = tx >> 6;
    const int lane = tx & 63;
    const int bm   = blockIdx.x * 32;
    const int g    = wave >> 1;
    const int h    = wave & 1;
    const int rs   = lane >> 2;
    const int chn  = (lane & 3) ^ SWZ(rs);
    const int m    = lane & 15;
    const int quad = lane >> 4;
    const int slot = quad ^ SWZ(m);

    w2s[tx] = l2W[tx];

    // prefetch stage-1 chunk0
    if (wave < 2) {
        int ar = bm + wave * 16 + rs; if (ar >= nrows) ar = nrows - 1;
        GLDS16(nid + (size_t)ar * 128 + chn * 8, Atile + wave * 512);
    }
#pragma unroll
    for (int i = 0; i < 2; ++i) {
        int seg = wave + 4 * i;
        int col = seg * 16 + rs;
        GLDS16(Wt + (size_t)col * 256 + chn * 8, Btile + seg * 512);
    }

    // ---- gather ----
    {
        const int n0   = bm + wave * 8;
        const int nend = n0 + 8;
        int n    = n0;
        const int base = off[n0 < NN ? n0 : NN];
        const int end  = off[nend < NN ? nend : NN];
        int nb = (n < NN) ? off[n + 1] : 0x7fffffff;
        const ushort* hp = hw + lane * 2;
        const float g0 = gbias[lane * 2], g1 = gbias[lane * 2 + 1];
        float a0 = 0.f, a1 = 0.f;
        const int c32g = lane >> 4;
        const int ksg  = (lane >> 2) & 3;
        const int wth  = (2 * lane) & 7;
        for (int chunk = base; chunk < end; chunk += 64) {
            int idx = chunk + lane;
            int pk = (idx < end) ? (int)esw[idx] : 0;
            int cnt = end - chunk; if (cnt > 64) cnt = 64;
            int cnt16 = (cnt + 15) & ~15;
            for (int j = 0; j < cnt16; j += 16) {
                int pp[16];
                unsigned int rv[16];
#pragma unroll
                for (int k = 0; k < 16; ++k)
                    pp[k] = __builtin_amdgcn_readlane(pk, j + k);
#pragma unroll
                for (int k = 0; k < 16; ++k)
                    rv[k] = *(const unsigned int*)(hp + (size_t)(pp[k] & 0x1FFFF) * 128);
#pragma unroll
                for (int k = 0; k < 16; ++k) {
                    int e = chunk + j + k;
                    while (e == nb) {
                        int row = n - bm;
                        unsigned int o = (unsigned int)f2bf(fmaxf(a0 + g0, 0.f)) |
                                         ((unsigned int)f2bf(fmaxf(a1 + g1, 0.f)) << 16);
                        int pos = ksg ^ SWZ(row & 15);
                        *(unsigned int*)(AggXt + row * 128 +
                            ((c32g * 32 + pos * 8 + wth) ^ ((row & 1) << 5))) = o;
                        a0 = 0.f; a1 = 0.f;
                        ++n;
                        nb = (n < nend && n < NN) ? off[n + 1] : 0x7fffffff;
                    }
                    float w = bf2f((ushort)((unsigned int)pp[k] >> 17));
                    a0 = fmaf(bf2f((ushort)(rv[k] & 0xffff)), w, a0);
                    a1 = fmaf(bf2f((ushort)(rv[k] >> 16)),    w, a1);
                }
            }
        }
        while (n < nend) {
            int row = n - bm;
            unsigned int o = (unsigned int)f2bf(fmaxf(a0 + g0, 0.f)) |
                             ((unsigned int)f2bf(fmaxf(a1 + g1, 0.f)) << 16);
            int pos = ksg ^ SWZ(row & 15);
            *(unsigned int*)(AggXt + row * 128 +
                ((c32g * 32 + pos * 8 + wth) ^ ((row & 1) << 5))) = o;
            a0 = 0.f; a1 = 0.f;
            ++n;
        }
    }

    f32x4 acc[4];
#pragma unroll
    for (int t = 0; t < 4; ++t) acc[t] = (f32x4){0.f, 0.f, 0.f, 0.f};

    // ---- stage 1: X = relu(nid@top + Agg@bot + b5), K=256 ----
    for (int c8 = 0; c8 < 8; ++c8) {
        int kk = c8 * 32;
        if (c8 > 0) {
            if (c8 < 4 && wave < 2) {
                int ar = bm + wave * 16 + rs; if (ar >= nrows) ar = nrows - 1;
                GLDS16(nid + (size_t)ar * 128 + kk + chn * 8, Atile + wave * 512);
            }
#pragma unroll
            for (int i = 0; i < 2; ++i) {
                int seg = wave + 4 * i;
                int col = seg * 16 + rs;
                GLDS16(Wt + (size_t)col * 256 + kk + chn * 8, Btile + seg * 512);
            }
        }
        __syncthreads();
        bf16x8 af;
        if (c8 < 4) {
            af = *(const bf16x8*)(Atile + (g * 16 + m) * 32 + slot * 8);
        } else {
            int row = g * 16 + m;
            af = *(const bf16x8*)(AggXt + row * 128 +
                 (((c8 - 4) * 32 + slot * 8) ^ ((row & 1) << 5)));
        }
#pragma unroll
        for (int t = 0; t < 4; ++t) {
            bf16x8 bfr = *(const bf16x8*)(Btile + (h * 64 + t * 16 + m) * 32 + slot * 8);
            acc[t] = __builtin_amdgcn_mfma_f32_16x16x32_bf16(af, bfr, acc[t], 0, 0, 0);
        }
        __syncthreads();
    }

    // prefetch stage-2 chunk0 (A from nid, B from Wl1)
    if (wave < 2) {
        int ar = bm + wave * 16 + rs; if (ar >= nrows) ar = nrows - 1;
        GLDS16(nid + (size_t)ar * 128 + chn * 8, Atile + wave * 512);
    }
#pragma unroll
    for (int i = 0; i < 2; ++i) {
        int seg = wave + 4 * i;
        int col = seg * 16 + rs;
        GLDS16(Wl1 + (size_t)col * 256 + chn * 8, Btile + seg * 512);
    }

    // ---- epilogue 1 -> Xt (= AggXt) ----
    {
        int rbase = g * 16 + quad * 4;
#pragma unroll
        for (int t = 0; t < 4; ++t) {
            int col = h * 64 + t * 16 + m;
            float bb = bias5[col];
            int c32 = col >> 5, within = col & 7, ks = (col >> 3) & 3;
#pragma unroll
            for (int r = 0; r < 4; ++r) {
                int row = rbase + r;
                int pos = ks ^ SWZ(row & 15);
                AggXt[row * 128 + ((c32 * 32 + pos * 8 + within) ^ ((row & 1) << 5))] =
                    f2bf(fmaxf(acc[t][r] + bb, 0.f));
            }
        }
    }
#pragma unroll
    for (int t = 0; t < 4; ++t) acc[t] = (f32x4){0.f, 0.f, 0.f, 0.f};
    __syncthreads();

    // ---- stage 2: HH = nid@l1t + X@l1b, K=256 ----
    for (int c8 = 0; c8 < 8; ++c8) {
        int kk = c8 * 32;
        if (c8 > 0) {
            if (c8 < 4 && wave < 2) {
                int ar = bm + wave * 16 + rs; if (ar >= nrows) ar = nrows - 1;
                GLDS16(nid + (size_t)ar * 128 + kk + chn * 8, Atile + wave * 512);
            }
#pragma unroll
            for (int i = 0; i < 2; ++i) {
                int seg = wave + 4 * i;
                int col = seg * 16 + rs;
                GLDS16(Wl1 + (size_t)col * 256 + kk + chn * 8, Btile + seg * 512);
            }
        }
        __syncthreads();
        bf16x8 af;
        if (c8 < 4) {
            af = *(const bf16x8*)(Atile + (g * 16 + m) * 32 + slot * 8);
        } else {
            int row = g * 16 + m;
            af = *(const bf16x8*)(AggXt + row * 128 +
                 (((c8 - 4) * 32 + slot * 8) ^ ((row & 1) << 5)));
        }
#pragma unroll
        for (int t = 0; t < 4; ++t) {
            bf16x8 bfr = *(const bf16x8*)(Btile + (h * 64 + t * 16 + m) * 32 + slot * 8);
            acc[t] = __builtin_amdgcn_mfma_f32_16x16x32_bf16(af, bfr, acc[t], 0, 0, 0);
        }
        __syncthreads();
    }

    // ---- epilogue: relu(HH+l1b) @ l2W, pair-reduce, sigmoid ----
    float bb[4];
#pragma unroll
    for (int t = 0; t < 4; ++t) bb[t] = l1b[h * 64 + t * 16 + m];
    float pr0[4], pr1[4];
#pragma unroll
    for (int r = 0; r < 4; ++r) {
        float p0 = 0.f, p1 = 0.f;
#pragma unroll
        for (int t = 0; t < 4; ++t) {
            int col = h * 64 + t * 16 + m;
            float v = fmaxf(acc[t][r] + bb[t], 0.f);
            p0 = fmaf(v, w2s[col * 2 + 0], p0);
            p1 = fmaf(v, w2s[col * 2 + 1], p1);
        }
#pragma unroll
        for (int mask = 1; mask < 16; mask <<= 1) {
            p0 += __shfl_xor(p0, mask);
            p1 += __shfl_xor(p1, mask);
        }
        pr0[r] = p0; pr1[r] = p1;
    }
    if (h == 1 && m == 0) {
#pragma unroll
        for (int r = 0; r < 4; ++r) {
            int lrow = g * 16 + quad * 4 + r;
            pbuf[lrow][0] = pr0[r];
            pbuf[lrow][1] = pr1[r];
        }
    }
    __syncthreads();
    if (h == 0 && m == 0) {
        float b20 = l2b[0], b21 = l2b[1];
#pragma unroll
        for (int r = 0; r < 4; ++r) {
            int lrow = g * 16 + quad * 4 + r;
            int row = bm + lrow;
            if (row < nrows) {
                float p0 = pr0[r] + pbuf[lrow][0] + b20;
                float p1 = pr1[r] + pbuf[lrow][1] + b21;
                out[(size_t)row * 2 + 0] = 1.f / (1.f + __expf(-p0));
                out[(size_t)row * 2 + 1] = 1.f / (1.f + __expf(-p1));
            }
        }
    }
}

// ---------------------------------------------------------------- launch
extern "C" void kernel_launch(void* const* d_in, const int* in_sizes, int n_in,
                              void* d_out, int out_size, void* d_ws, size_t ws_size,
                              hipStream_t stream)
{
    const float* x    = (const float*)d_in[0];
    const int*   esrc = (const int*)  d_in[1];
    const int*   edst = (const int*)  d_in[2];
    const float* ew   = (const float*)d_in[3];
    const float* preW = (const float*)d_in[4];
    const float* preb = (const float*)d_in[5];
    const float* f1W  = (const float*)d_in[6];
    const float* f1b  = (const float*)d_in[7];
    const float* f2W  = (const float*)d_in[8];
    const float* f2b  = (const float*)d_in[9];
    const float* gW   = (const float*)d_in[10];
    const float* gb   = (const float*)d_in[11];
    const float* fgW  = (const float*)d_in[12];
    const float* fgb  = (const float*)d_in[13];
    const float* l1W  = (const float*)d_in[14];
    const float* l1b  = (const float*)d_in[15];
    const float* l2W  = (const float*)d_in[16];
    const float* l2b  = (const float*)d_in[17];
    float* out = (float*)d_out;

    ushort* wt   = (ushort*)d_ws;
    ushort* wf1  = wt;                          //   4096
    ushort* wf2  = wf1 + 4096;                  //   4096
    ushort* wg   = wf2 + 4096;                  //  98304
    ushort* wfg  = wg  + 98304;                 // 196608
    ushort* wl1  = wfg + 196608;                //  32768
    ushort* h0b  = wl1 + 32768;                 // N*32
    ushort* nidb = h0b  + (size_t)NN * 32;      // N*128
    ushort* hwb  = nidb + (size_t)NN * 128;     // N*128 row-major (ping)
    ushort* hwb2 = hwb  + (size_t)NN * 128;     // N*128 row-major (pong)
    ushort* endu = hwb2 + (size_t)NN * 128;
    unsigned int* esw      = (unsigned int*)(((uintptr_t)endu + 15) & ~(uintptr_t)15);
    unsigned int* stage_pk = esw + NE;
    int*          bcnt     = (int*)(stage_pk + NE);   // NB
    int*          bbase    = bcnt + NB + 1;           // NB+1
    int*          bcur     = bbase + NB + 1;          // NB
    int*          off      = bcur + NB + 1;           // NN+1
    unsigned char* stage_dl = (unsigned char*)(off + NN + 2);  // NE bytes

    const int gblocks  = (NN + 63) / 64;        // 782  (fc1f0 tiles)
    const int g32      = (NN + 31) / 32;        // 1563 (layer tiles)
    const int eblocks  = (NE + 1023) / 1024;    // 586

    // ---- CSR build + preproc + weight conversion (merged where independent) ----
    hipMemsetAsync(bcnt, 0, (size_t)NB * sizeof(int), stream);
    convbh_kernel<<<1312 + eblocks, 256, 0, stream>>>(f1W, f2W, gW, fgW, l1W, wt,
                                                      edst, bcnt);
    bscan_kernel<<<1, 512, 0, stream>>>(bcnt, bbase, bcur);
    pass1_kernel<<<eblocks, 256, 0, stream>>>(esrc, edst, ew, bcur, stage_pk, stage_dl);
    p2pre_kernel<<<NB + (NN + 255) / 256, 256, 0, stream>>>(stage_pk, stage_dl, bbase,
                                                            esw, off, x, preW, preb, h0b);

    // ---- network ----
    fc1f0_kernel<<<2 * gblocks, 128, 0, stream>>>(h0b, wf1, f1b, nidb,
                                                  wf2, f2b, wg, hwb);
    ushort* cur = hwb;
    ushort* nxt = hwb2;
    for (int l = 0; l < 5; ++l) {
        gemm_gather<<<g32, 256, 0, stream>>>(cur, esw, off,
                                             gb + (size_t)l * 128, nidb,
                                             wfg + (size_t)l * 32768,
                                             fgb + (size_t)l * 128,
                                             wg + (size_t)(l + 1) * 16384,
                                             nxt, NN);
        ushort* tmp = cur; cur = nxt; nxt = tmp;
    }
    gemm_last<<<g32, 256, 0, stream>>>(cur, esw, off,
                                       gb + (size_t)5 * 128, nidb,
                                       wfg + (size_t)5 * 32768,
                                       fgb + (size_t)5 * 128,
                                       wl1, l1b, l2W, l2b, out, NN);
}

// Round 8
// 373.866 us; speedup vs baseline: 1.2426x; 1.1104x over previous
//
#include <hip/hip_runtime.h>
#include <cstddef>
#include <cstdint>

#define NN 50000
#define NE 600000
#define NB 391                    // buckets of 128 dst nodes

typedef __attribute__((ext_vector_type(8))) short bf16x8;
typedef __attribute__((ext_vector_type(4))) float f32x4;

#define SWZ(x) (((x) ^ ((x) >> 2)) & 3)

#define GLDS16(src, dst)                                                     \
    __builtin_amdgcn_global_load_lds(                                        \
        (const __attribute__((address_space(1))) void*)(src),                \
        (__attribute__((address_space(3))) void*)(dst), 16, 0, 0)

__device__ __forceinline__ float bf2f(ushort u) {
    return __uint_as_float(((uint32_t)u) << 16);
}
__device__ __forceinline__ ushort f2bf(float f) {   // round-to-nearest-even
    uint32_t b = __float_as_uint(f);
    return (ushort)((b + 0x7FFF + ((b >> 16) & 1)) >> 16);
}

// ---------------------------------------------------------------- convert_weights + bhist (merged, independent)
__global__ __launch_bounds__(256)
void convbh_kernel(const float* __restrict__ f1W, const float* __restrict__ f2W,
                   const float* __restrict__ gW, const float* __restrict__ fgW,
                   const float* __restrict__ l1W, ushort* __restrict__ wt,
                   const int* __restrict__ dst, int* __restrict__ bcnt)
{
    if (blockIdx.x < 1312) {
        int i = blockIdx.x * 256 + threadIdx.x;          // 0 .. 335871
        if (i >= 335872) return;
        float v;
        if (i < 4096) {                                  // wf1
            int c = i >> 5, k = i & 31;
            v = f1W[k * 128 + c];
        } else if (i < 8192) {                           // wf2
            int j = i - 4096; int c = j >> 5, k = j & 31;
            v = f2W[k * 128 + c];
        } else if (i < 8192 + 98304) {                   // wg
            int j = i - 8192; int l = j >> 14, r = j & 16383;
            int c = r >> 7, k = r & 127;
            v = gW[l * 16384 + k * 128 + c];
        } else if (i < 8192 + 98304 + 196608) {          // wfg
            int j = i - (8192 + 98304); int l = j >> 15, r = j & 32767;
            int c = r >> 8, k = r & 255;
            v = fgW[l * 32768 + k * 128 + c];
        } else {                                         // wl1
            int j = i - (8192 + 98304 + 196608);
            int c = j >> 8, k = j & 255;
            v = l1W[k * 128 + c];
        }
        wt[i] = f2bf(v);
    } else {
        __shared__ int h[NB];
        int tx = threadIdx.x;
        for (int i = tx; i < NB; i += 256) h[i] = 0;
        __syncthreads();
        int e0 = (blockIdx.x - 1312) * 1024;
#pragma unroll
        for (int k = 0; k < 4; ++k) {
            int e = e0 + k * 256 + tx;
            if (e < NE) atomicAdd(&h[dst[e] >> 7], 1);
        }
        __syncthreads();
        for (int i = tx; i < NB; i += 256)
            if (h[i]) atomicAdd(&bcnt[i], h[i]);
    }
}

// ---------------------------------------------------------------- bscan
__global__ __launch_bounds__(512)
void bscan_kernel(const int* __restrict__ bcnt, int* __restrict__ bbase,
                  int* __restrict__ bcur)
{
    __shared__ int buf[512];
    int t = threadIdx.x;
    int v = (t < NB) ? bcnt[t] : 0;
    buf[t] = v;
    __syncthreads();
    for (int s = 1; s < 512; s <<= 1) {
        int u = (t >= s) ? buf[t - s] : 0;
        __syncthreads();
        buf[t] += u;
        __syncthreads();
    }
    if (t < NB) {
        int ex = buf[t] - v;
        bbase[t] = ex;
        bcur[t]  = ex;
    }
    if (t == 0) bbase[NB] = NE;
}

// ---------------------------------------------------------------- pass1
__global__ __launch_bounds__(256)
void pass1_kernel(const int* __restrict__ src, const int* __restrict__ dst,
                  const float* __restrict__ w, int* __restrict__ bcur,
                  unsigned int* __restrict__ stage_pk,
                  unsigned char* __restrict__ stage_dl)
{
    __shared__ int cnt[NB];
    __shared__ int gbase[NB];
    int tx = threadIdx.x;
    for (int i = tx; i < NB; i += 256) cnt[i] = 0;
    __syncthreads();
    int e0 = blockIdx.x * 1024;
    int myd[4], myrank[4];
    unsigned int mypk[4];
#pragma unroll
    for (int k = 0; k < 4; ++k) {
        int e = e0 + k * 256 + tx;
        if (e < NE) {
            int d = dst[e];
            myd[k]    = d;
            mypk[k]   = (unsigned int)src[e] | ((unsigned int)f2bf(w[e]) << 17);
            myrank[k] = atomicAdd(&cnt[d >> 7], 1);
        } else {
            myd[k] = -1;
        }
    }
    __syncthreads();
    for (int i = tx; i < NB; i += 256)
        gbase[i] = cnt[i] ? atomicAdd(&bcur[i], cnt[i]) : 0;
    __syncthreads();
#pragma unroll
    for (int k = 0; k < 4; ++k) {
        if (myd[k] >= 0) {
            int p = gbase[myd[k] >> 7] + myrank[k];
            stage_pk[p] = mypk[k];
            stage_dl[p] = (unsigned char)(myd[k] & 127);
        }
    }
}

// ---------------------------------------------------------------- pass2 + preproc (merged, independent)
__global__ __launch_bounds__(256)
void p2pre_kernel(const unsigned int* __restrict__ stage_pk,
                  const unsigned char* __restrict__ stage_dl,
                  const int* __restrict__ bbase,
                  unsigned int* __restrict__ esw, int* __restrict__ off,
                  const float* __restrict__ x, const float* __restrict__ preW,
                  const float* __restrict__ preb, ushort* __restrict__ h0b)
{
    if (blockIdx.x < NB) {
        __shared__ int h[128];
        __shared__ int lofs[128];
        int b    = blockIdx.x;
        int tx   = threadIdx.x;
        int base = bbase[b];
        int cnt  = bbase[b + 1] - base;
        if (tx < 128) h[tx] = 0;
        __syncthreads();
        for (int i = tx; i < cnt; i += 256)
            atomicAdd(&h[stage_dl[base + i]], 1);
        __syncthreads();
        if (tx == 0) {
            int run = 0;
            for (int i = 0; i < 128; ++i) { lofs[i] = run; run += h[i]; }
        }
        __syncthreads();
        int node0 = b * 128;
        if (tx < 128) {
            int n = node0 + tx;
            if (n < NN) off[n] = base + lofs[tx];
            h[tx] = 0;                       // reset for rank pass
        }
        if (b == NB - 1 && tx == 0) off[NN] = NE;
        __syncthreads();
        for (int i = tx; i < cnt; i += 256) {
            int d = stage_dl[base + i];
            int r = atomicAdd(&h[d], 1);
            esw[base + lofs[d] + r] = stage_pk[base + i];
        }
    } else {
        __shared__ float Wl[512];
        __shared__ float bl[32];
        int tx = threadIdx.x;
        Wl[tx]       = preW[tx];
        Wl[tx + 256] = preW[tx + 256];
        if (tx < 32) bl[tx] = preb[tx];
        __syncthreads();
        int n = (blockIdx.x - NB) * 256 + tx;
        if (n >= NN) return;
        float xr[16];
        const float4* xp = (const float4*)(x + (size_t)n * 16);
#pragma unroll
        for (int q = 0; q < 4; ++q) {
            float4 v = xp[q];
            xr[q*4+0]=v.x; xr[q*4+1]=v.y; xr[q*4+2]=v.z; xr[q*4+3]=v.w;
        }
        float acc[32];
#pragma unroll
        for (int c = 0; c < 32; ++c) acc[c] = bl[c];
#pragma unroll
        for (int k = 0; k < 16; ++k)
#pragma unroll
            for (int c = 0; c < 32; ++c)
                acc[c] = fmaf(xr[k], Wl[k*32+c], acc[c]);
        ushort4* op = (ushort4*)(h0b + (size_t)n * 32);
#pragma unroll
        for (int q = 0; q < 8; ++q) {
            ushort4 v;
            v.x = f2bf(fmaxf(acc[q*4+0], 0.f));
            v.y = f2bf(fmaxf(acc[q*4+1], 0.f));
            v.z = f2bf(fmaxf(acc[q*4+2], 0.f));
            v.w = f2bf(fmaxf(acc[q*4+3], 0.f));
            op[q] = v;
        }
    }
}

// ---------------------------------------------------------------- fc_in1 + fused layer0 (merged; both read h0b only)
__global__ __launch_bounds__(128)
void fc1f0_kernel(const ushort* __restrict__ h0b,
                  const ushort* __restrict__ wf1, const float* __restrict__ f1b,
                  ushort* __restrict__ nidb,
                  const ushort* __restrict__ wf2, const float* __restrict__ f2b,
                  const ushort* __restrict__ wg, ushort* __restrict__ hwb)
{
    __shared__ ushort Atile[64 * 32];
    __shared__ ushort Btile[128 * 32];
    __shared__ ushort Xt[64 * 128];
    const int tx   = threadIdx.x;
    const int wave = tx >> 6;
    const int lane = tx & 63;
    const int rs  = lane >> 2;
    const int chn = (lane & 3) ^ SWZ(rs);
    const int m    = lane & 15;
    const int quad = lane >> 4;
    const int slot = quad ^ SWZ(m);

    if (blockIdx.x < 782) {
        // ---- fc_in1 path (K=32) ----
        const int bm = blockIdx.x * 64;
        f32x4 acc0[8], acc1[8];
#pragma unroll
        for (int t = 0; t < 8; ++t) {
            acc0[t] = (f32x4){0.f, 0.f, 0.f, 0.f};
            acc1[t] = (f32x4){0.f, 0.f, 0.f, 0.f};
        }
#pragma unroll
        for (int i = 0; i < 2; ++i) {
            int seg = wave + 2 * i;
            int row = seg * 16 + rs;
            int ar  = bm + row; if (ar >= NN) ar = NN - 1;
            GLDS16(h0b + (size_t)ar * 32 + chn * 8, Atile + seg * 512);
        }
#pragma unroll
        for (int i = 0; i < 4; ++i) {
            int seg = wave + 2 * i;
            int col = seg * 16 + rs;
            GLDS16(wf1 + (size_t)col * 32 + chn * 8, Btile + seg * 512);
        }
        __syncthreads();
        bf16x8 af0 = *(const bf16x8*)(Atile + (wave * 32 + m) * 32 + slot * 8);
        bf16x8 af1 = *(const bf16x8*)(Atile + (wave * 32 + 16 + m) * 32 + slot * 8);
#pragma unroll
        for (int t = 0; t < 8; ++t) {
            bf16x8 bfr = *(const bf16x8*)(Btile + (t * 16 + m) * 32 + slot * 8);
            acc0[t] = __builtin_amdgcn_mfma_f32_16x16x32_bf16(af0, bfr, acc0[t], 0, 0, 0);
            acc1[t] = __builtin_amdgcn_mfma_f32_16x16x32_bf16(af1, bfr, acc1[t], 0, 0, 0);
        }
        __syncthreads();
#pragma unroll
        for (int half = 0; half < 2; ++half) {
            const int orow0 = bm + wave * 32 + half * 16 + quad * 4;
#pragma unroll
            for (int t = 0; t < 8; ++t) {
                int col = t * 16 + m;
                float bb = f1b[col];
                f32x4 a = half ? acc1[t] : acc0[t];
#pragma unroll
                for (int r = 0; r < 4; ++r) {
                    int row = orow0 + r;
                    if (row < NN)
                        nidb[(size_t)row * 128 + col] = f2bf(fmaxf(a[r] + bb, 0.f));
                }
            }
        }
    } else {
        // ---- fused layer0 path: X = relu(h0b@wf2+f2b); hwb = X@wg0 ----
        const int bm = (blockIdx.x - 782) * 64;
        f32x4 acc0[8], acc1[8];
#pragma unroll
        for (int t = 0; t < 8; ++t) {
            acc0[t] = (f32x4){0.f, 0.f, 0.f, 0.f};
            acc1[t] = (f32x4){0.f, 0.f, 0.f, 0.f};
        }
#pragma unroll
        for (int i = 0; i < 2; ++i) {
            int seg = wave + 2 * i;
            int row = seg * 16 + rs;
            int ar  = bm + row; if (ar >= NN) ar = NN - 1;
            GLDS16(h0b + (size_t)ar * 32 + chn * 8, Atile + seg * 512);
        }
#pragma unroll
        for (int i = 0; i < 4; ++i) {
            int seg = wave + 2 * i;
            int col = seg * 16 + rs;
            GLDS16(wf2 + (size_t)col * 32 + chn * 8, Btile + seg * 512);
        }
        __syncthreads();
        {
            bf16x8 af0 = *(const bf16x8*)(Atile + (wave * 32 + m) * 32 + slot * 8);
            bf16x8 af1 = *(const bf16x8*)(Atile + (wave * 32 + 16 + m) * 32 + slot * 8);
#pragma unroll
            for (int t = 0; t < 8; ++t) {
                bf16x8 bfr = *(const bf16x8*)(Btile + (t * 16 + m) * 32 + slot * 8);
                acc0[t] = __builtin_amdgcn_mfma_f32_16x16x32_bf16(af0, bfr, acc0[t], 0, 0, 0);
                acc1[t] = __builtin_amdgcn_mfma_f32_16x16x32_bf16(af1, bfr, acc1[t], 0, 0, 0);
            }
        }
        __syncthreads();
#pragma unroll
        for (int half = 0; half < 2; ++half) {
            int rbase = wave * 32 + half * 16 + quad * 4;
#pragma unroll
            for (int t = 0; t < 8; ++t) {
                int col = t * 16 + m;
                float bb = f2b[col];
                int c32 = col >> 5, within = col & 7, ks = (col >> 3) & 3;
                f32x4 a = half ? acc1[t] : acc0[t];
#pragma unroll
                for (int r = 0; r < 4; ++r) {
                    int row = rbase + r;
                    int pos = ks ^ SWZ(row & 15);
                    Xt[row * 128 + c32 * 32 + pos * 8 + within] =
                        f2bf(fmaxf(a[r] + bb, 0.f));
                }
            }
        }
#pragma unroll
        for (int t = 0; t < 8; ++t) {
            acc0[t] = (f32x4){0.f, 0.f, 0.f, 0.f};
            acc1[t] = (f32x4){0.f, 0.f, 0.f, 0.f};
        }
        __syncthreads();
        for (int c32 = 0; c32 < 4; ++c32) {
            int kk = c32 * 32;
#pragma unroll
            for (int i = 0; i < 4; ++i) {
                int seg = wave + 2 * i;
                int col = seg * 16 + rs;
                GLDS16(wg + (size_t)col * 128 + kk + chn * 8, Btile + seg * 512);
            }
            __syncthreads();
            bf16x8 af0 = *(const bf16x8*)(Xt + (wave * 32 + m) * 128 + kk + slot * 8);
            bf16x8 af1 = *(const bf16x8*)(Xt + (wave * 32 + 16 + m) * 128 + kk + slot * 8);
#pragma unroll
            for (int t = 0; t < 8; ++t) {
                bf16x8 bfr = *(const bf16x8*)(Btile + (t * 16 + m) * 32 + slot * 8);
                acc0[t] = __builtin_amdgcn_mfma_f32_16x16x32_bf16(af0, bfr, acc0[t], 0, 0, 0);
                acc1[t] = __builtin_amdgcn_mfma_f32_16x16x32_bf16(af1, bfr, acc1[t], 0, 0, 0);
            }
            __syncthreads();
        }
#pragma unroll
        for (int half = 0; half < 2; ++half) {
            const int orow0 = bm + wave * 32 + half * 16 + quad * 4;
#pragma unroll
            for (int t = 0; t < 8; ++t) {
                int col = t * 16 + m;
                f32x4 a = half ? acc1[t] : acc0[t];
#pragma unroll
                for (int r = 0; r < 4; ++r) {
                    int row = orow0 + r;
                    if (row < NN)
                        hwb[(size_t)row * 128 + col] = f2bf(a[r]);
                }
            }
        }
    }
}

// ---------------------------------------------------------------- fused gather + GEMM (64-row, 8 waves)
// wave w: gathers 8 nodes (rows w*8..w*8+7) into AggXt (swizzled+parity-XOR layout);
// GEMM: wave-pair g=w>>1 owns rows g*16..+15, col-half h=w&1 owns cols h*64..+63.
// AggXt doubles as Xt after stage 1 (disjoint lifetimes).
__global__ __launch_bounds__(512)
void gemm_gather(const ushort* __restrict__ hw,
                 const unsigned int* __restrict__ esw,
                 const int* __restrict__ off,
                 const float* __restrict__ gbias,
                 const ushort* __restrict__ nid,
                 const ushort* __restrict__ Wt,     // [col 128][k 256]
                 const float* __restrict__ bias,
                 const ushort* __restrict__ Wg,     // [col 128][k 128]
                 ushort* __restrict__ out_hw, int nrows)
{
    __shared__ ushort Atile[64 * 32];
    __shared__ ushort Btile[128 * 32];
    __shared__ ushort AggXt[64 * 128];
    const int tx   = threadIdx.x;
    const int wave = tx >> 6;          // 0..7
    const int lane = tx & 63;
    const int bm   = blockIdx.x * 64;
    const int g    = wave >> 1;        // row-group
    const int h    = wave & 1;         // col-half
    const int rs   = lane >> 2;
    const int chn  = (lane & 3) ^ SWZ(rs);
    const int m    = lane & 15;
    const int quad = lane >> 4;
    const int slot = quad ^ SWZ(m);

    // prefetch stage-1 chunk0 (lands during gather)
    if (wave < 4) {
        int ar = bm + wave * 16 + rs; if (ar >= nrows) ar = nrows - 1;
        GLDS16(nid + (size_t)ar * 128 + chn * 8, Atile + wave * 512);
    }
    {
        int col = wave * 16 + rs;
        GLDS16(Wt + (size_t)col * 256 + chn * 8, Btile + wave * 512);
    }

    // ---- gather: 8 dst nodes per wave -> AggXt rows ----
    {
        const int n0   = bm + wave * 8;
        const int nend = n0 + 8;
        int n    = n0;
        const int base = off[n0 < NN ? n0 : NN];
        const int end  = off[nend < NN ? nend : NN];
        int nb = (n < NN) ? off[n + 1] : 0x7fffffff;
        const ushort* hp = hw + lane * 2;
        const float g0 = gbias[lane * 2], g1 = gbias[lane * 2 + 1];
        float a0 = 0.f, a1 = 0.f;
        const int c32g = lane >> 4;
        const int ksg  = (lane >> 2) & 3;
        const int wth  = (2 * lane) & 7;
        for (int chunk = base; chunk < end; chunk += 64) {
            int idx = chunk + lane;
            int pk = (idx < end) ? (int)esw[idx] : 0;
            int cnt = end - chunk; if (cnt > 64) cnt = 64;
            int cnt16 = (cnt + 15) & ~15;
            for (int j = 0; j < cnt16; j += 16) {
                int pp[16];
                unsigned int rv[16];
#pragma unroll
                for (int k = 0; k < 16; ++k)
                    pp[k] = __builtin_amdgcn_readlane(pk, j + k);
#pragma unroll
                for (int k = 0; k < 16; ++k)
                    rv[k] = *(const unsigned int*)(hp + (size_t)(pp[k] & 0x1FFFF) * 128);
#pragma unroll
                for (int k = 0; k < 16; ++k) {
                    int e = chunk + j + k;
                    while (e == nb) {                 // node boundary: flush node n
                        int row = n - bm;
                        unsigned int o = (unsigned int)f2bf(fmaxf(a0 + g0, 0.f)) |
                                         ((unsigned int)f2bf(fmaxf(a1 + g1, 0.f)) << 16);
                        int pos = ksg ^ SWZ(row & 15);
                        *(unsigned int*)(AggXt + row * 128 +
                            ((c32g * 32 + pos * 8 + wth) ^ ((row & 1) << 5))) = o;
                        a0 = 0.f; a1 = 0.f;
                        ++n;
                        nb = (n < nend && n < NN) ? off[n + 1] : 0x7fffffff;
                    }
                    float w = bf2f((ushort)((unsigned int)pp[k] >> 17));
                    a0 = fmaf(bf2f((ushort)(rv[k] & 0xffff)), w, a0);
                    a1 = fmaf(bf2f((ushort)(rv[k] >> 16)),    w, a1);
                }
            }
        }
        while (n < nend) {                            // flush remaining rows
            int row = n - bm;
            unsigned int o = (unsigned int)f2bf(fmaxf(a0 + g0, 0.f)) |
                             ((unsigned int)f2bf(fmaxf(a1 + g1, 0.f)) << 16);
            int pos = ksg ^ SWZ(row & 15);
            *(unsigned int*)(AggXt + row * 128 +
                ((c32g * 32 + pos * 8 + wth) ^ ((row & 1) << 5))) = o;
            a0 = 0.f; a1 = 0.f;
            ++n;
        }
    }

    f32x4 acc[4];
#pragma unroll
    for (int t = 0; t < 4; ++t) acc[t] = (f32x4){0.f, 0.f, 0.f, 0.f};

    // ---- stage 1: X = relu(nid@top + Agg@bot + bias), K=256 ----
    for (int c8 = 0; c8 < 8; ++c8) {
        int kk = c8 * 32;
        if (c8 > 0) {
            if (c8 < 4 && wave < 4) {
                int ar = bm + wave * 16 + rs; if (ar >= nrows) ar = nrows - 1;
                GLDS16(nid + (size_t)ar * 128 + kk + chn * 8, Atile + wave * 512);
            }
            int col = wave * 16 + rs;
            GLDS16(Wt + (size_t)col * 256 + kk + chn * 8, Btile + wave * 512);
        }
        __syncthreads();
        bf16x8 af;
        if (c8 < 4) {
            af = *(const bf16x8*)(Atile + (g * 16 + m) * 32 + slot * 8);
        } else {
            int row = g * 16 + m;
            af = *(const bf16x8*)(AggXt + row * 128 +
                 (((c8 - 4) * 32 + slot * 8) ^ ((row & 1) << 5)));
        }
#pragma unroll
        for (int t = 0; t < 4; ++t) {
            bf16x8 bfr = *(const bf16x8*)(Btile + (h * 64 + t * 16 + m) * 32 + slot * 8);
            acc[t] = __builtin_amdgcn_mfma_f32_16x16x32_bf16(af, bfr, acc[t], 0, 0, 0);
        }
        __syncthreads();
    }

    // prefetch stage-2 chunk0 B (Btile free after final stage-1 barrier)
    {
        int col = wave * 16 + rs;
        GLDS16(Wg + (size_t)col * 128 + chn * 8, Btile + wave * 512);
    }

    // ---- epilogue 1: bias+relu -> Xt (= AggXt), zero acc ----
    {
        int rbase = g * 16 + quad * 4;
#pragma unroll
        for (int t = 0; t < 4; ++t) {
            int col = h * 64 + t * 16 + m;
            float bb = bias[col];
            int c32 = col >> 5, within = col & 7, ks = (col >> 3) & 3;
#pragma unroll
            for (int r = 0; r < 4; ++r) {
                int row = rbase + r;
                int pos = ks ^ SWZ(row & 15);
                AggXt[row * 128 + ((c32 * 32 + pos * 8 + within) ^ ((row & 1) << 5))] =
                    f2bf(fmaxf(acc[t][r] + bb, 0.f));
            }
        }
    }
#pragma unroll
    for (int t = 0; t < 4; ++t) acc[t] = (f32x4){0.f, 0.f, 0.f, 0.f};

    // ---- stage 2: out_hw = X @ Wg^T (K=128) ----
    for (int c4 = 0; c4 < 4; ++c4) {
        int kk = c4 * 32;
        if (c4 > 0) {
            int col = wave * 16 + rs;
            GLDS16(Wg + (size_t)col * 128 + kk + chn * 8, Btile + wave * 512);
        }
        __syncthreads();
        int row = g * 16 + m;
        bf16x8 af = *(const bf16x8*)(AggXt + row * 128 +
                    ((kk + slot * 8) ^ ((row & 1) << 5)));
#pragma unroll
        for (int t = 0; t < 4; ++t) {
            bf16x8 bfr = *(const bf16x8*)(Btile + (h * 64 + t * 16 + m) * 32 + slot * 8);
            acc[t] = __builtin_amdgcn_mfma_f32_16x16x32_bf16(af, bfr, acc[t], 0, 0, 0);
        }
        __syncthreads();
    }

    // ---- epilogue 2 ----
    {
        const int orow0 = bm + g * 16 + quad * 4;
#pragma unroll
        for (int t = 0; t < 4; ++t) {
            int col = h * 64 + t * 16 + m;
#pragma unroll
            for (int r = 0; r < 4; ++r) {
                int row = orow0 + r;
                if (row < nrows)
                    out_hw[(size_t)row * 128 + col] = f2bf(acc[t][r]);
            }
        }
    }
}

// ---------------------------------------------------------------- last fused (gather + 2 GEMMs + head, 8 waves)
__global__ __launch_bounds__(512)
void gemm_last(const ushort* __restrict__ hw,
               const unsigned int* __restrict__ esw,
               const int* __restrict__ off,
               const float* __restrict__ gbias,
               const ushort* __restrict__ nid,
               const ushort* __restrict__ Wt, const float* __restrict__ bias5,
               const ushort* __restrict__ Wl1, const float* __restrict__ l1b,
               const float* __restrict__ l2W, const float* __restrict__ l2b,
               float* __restrict__ out, int nrows)
{
    __shared__ ushort Atile[64 * 32];
    __shared__ ushort Btile[128 * 32];
    __shared__ ushort AggXt[64 * 128];
    __shared__ float  w2s[256];
    __shared__ float  pbuf[64][2];
    const int tx   = threadIdx.x;
    const int wave = tx >> 6;
    const int lane = tx & 63;
    const int bm   = blockIdx.x * 64;
    const int g    = wave >> 1;
    const int h    = wave & 1;
    const int rs   = lane >> 2;
    const int chn  = (lane & 3) ^ SWZ(rs);
    const int m    = lane & 15;
    const int quad = lane >> 4;
    const int slot = quad ^ SWZ(m);

    if (tx < 256) w2s[tx] = l2W[tx];

    // prefetch stage-1 chunk0
    if (wave < 4) {
        int ar = bm + wave * 16 + rs; if (ar >= nrows) ar = nrows - 1;
        GLDS16(nid + (size_t)ar * 128 + chn * 8, Atile + wave * 512);
    }
    {
        int col = wave * 16 + rs;
        GLDS16(Wt + (size_t)col * 256 + chn * 8, Btile + wave * 512);
    }

    // ---- gather ----
    {
        const int n0   = bm + wave * 8;
        const int nend = n0 + 8;
        int n    = n0;
        const int base = off[n0 < NN ? n0 : NN];
        const int end  = off[nend < NN ? nend : NN];
        int nb = (n < NN) ? off[n + 1] : 0x7fffffff;
        const ushort* hp = hw + lane * 2;
        const float g0 = gbias[lane * 2], g1 = gbias[lane * 2 + 1];
        float a0 = 0.f, a1 = 0.f;
        const int c32g = lane >> 4;
        const int ksg  = (lane >> 2) & 3;
        const int wth  = (2 * lane) & 7;
        for (int chunk = base; chunk < end; chunk += 64) {
            int idx = chunk + lane;
            int pk = (idx < end) ? (int)esw[idx] : 0;
            int cnt = end - chunk; if (cnt > 64) cnt = 64;
            int cnt16 = (cnt + 15) & ~15;
            for (int j = 0; j < cnt16; j += 16) {
                int pp[16];
                unsigned int rv[16];
#pragma unroll
                for (int k = 0; k < 16; ++k)
                    pp[k] = __builtin_amdgcn_readlane(pk, j + k);
#pragma unroll
                for (int k = 0; k < 16; ++k)
                    rv[k] = *(const unsigned int*)(hp + (size_t)(pp[k] & 0x1FFFF) * 128);
#pragma unroll
                for (int k = 0; k < 16; ++k) {
                    int e = chunk + j + k;
                    while (e == nb) {
                        int row = n - bm;
                        unsigned int o = (unsigned int)f2bf(fmaxf(a0 + g0, 0.f)) |
                                         ((unsigned int)f2bf(fmaxf(a1 + g1, 0.f)) << 16);
                        int pos = ksg ^ SWZ(row & 15);
                        *(unsigned int*)(AggXt + row * 128 +
                            ((c32g * 32 + pos * 8 + wth) ^ ((row & 1) << 5))) = o;
                        a0 = 0.f; a1 = 0.f;
                        ++n;
                        nb = (n < nend && n < NN) ? off[n + 1] : 0x7fffffff;
                    }
                    float w = bf2f((ushort)((unsigned int)pp[k] >> 17));
                    a0 = fmaf(bf2f((ushort)(rv[k] & 0xffff)), w, a0);
                    a1 = fmaf(bf2f((ushort)(rv[k] >> 16)),    w, a1);
                }
            }
        }
        while (n < nend) {
            int row = n - bm;
            unsigned int o = (unsigned int)f2bf(fmaxf(a0 + g0, 0.f)) |
                             ((unsigned int)f2bf(fmaxf(a1 + g1, 0.f)) << 16);
            int pos = ksg ^ SWZ(row & 15);
            *(unsigned int*)(AggXt + row * 128 +
                ((c32g * 32 + pos * 8 + wth) ^ ((row & 1) << 5))) = o;
            a0 = 0.f; a1 = 0.f;
            ++n;
        }
    }

    f32x4 acc[4];
#pragma unroll
    for (int t = 0; t < 4; ++t) acc[t] = (f32x4){0.f, 0.f, 0.f, 0.f};

    // ---- stage 1: X = relu(nid@top + Agg@bot + b5), K=256 ----
    for (int c8 = 0; c8 < 8; ++c8) {
        int kk = c8 * 32;
        if (c8 > 0) {
            if (c8 < 4 && wave < 4) {
                int ar = bm + wave * 16 + rs; if (ar >= nrows) ar = nrows - 1;
                GLDS16(nid + (size_t)ar * 128 + kk + chn * 8, Atile + wave * 512);
            }
            int col = wave * 16 + rs;
            GLDS16(Wt + (size_t)col * 256 + kk + chn * 8, Btile + wave * 512);
        }
        __syncthreads();
        bf16x8 af;
        if (c8 < 4) {
            af = *(const bf16x8*)(Atile + (g * 16 + m) * 32 + slot * 8);
        } else {
            int row = g * 16 + m;
            af = *(const bf16x8*)(AggXt + row * 128 +
                 (((c8 - 4) * 32 + slot * 8) ^ ((row & 1) << 5)));
        }
#pragma unroll
        for (int t = 0; t < 4; ++t) {
            bf16x8 bfr = *(const bf16x8*)(Btile + (h * 64 + t * 16 + m) * 32 + slot * 8);
            acc[t] = __builtin_amdgcn_mfma_f32_16x16x32_bf16(af, bfr, acc[t], 0, 0, 0);
        }
        __syncthreads();
    }

    // prefetch stage-2 chunk0 (A from nid, B from Wl1)
    if (wave < 4) {
        int ar = bm + wave * 16 + rs; if (ar >= nrows) ar = nrows - 1;
        GLDS16(nid + (size_t)ar * 128 + chn * 8, Atile + wave * 512);
    }
    {
        int col = wave * 16 + rs;
        GLDS16(Wl1 + (size_t)col * 256 + chn * 8, Btile + wave * 512);
    }

    // ---- epilogue 1 -> Xt (= AggXt) ----
    {
        int rbase = g * 16 + quad * 4;
#pragma unroll
        for (int t = 0; t < 4; ++t) {
            int col = h * 64 + t * 16 + m;
            float bb = bias5[col];
            int c32 = col >> 5, within = col & 7, ks = (col >> 3) & 3;
#pragma unroll
            for (int r = 0; r < 4; ++r) {
                int row = rbase + r;
                int pos = ks ^ SWZ(row & 15);
                AggXt[row * 128 + ((c32 * 32 + pos * 8 + within) ^ ((row & 1) << 5))] =
                    f2bf(fmaxf(acc[t][r] + bb, 0.f));
            }
        }
    }
#pragma unroll
    for (int t = 0; t < 4; ++t) acc[t] = (f32x4){0.f, 0.f, 0.f, 0.f};

    // ---- stage 2: HH = nid@l1t + X@l1b, K=256 ----
    for (int c8 = 0; c8 < 8; ++c8) {
        int kk = c8 * 32;
        if (c8 > 0) {
            if (c8 < 4 && wave < 4) {
                int ar = bm + wave * 16 + rs; if (ar >= nrows) ar = nrows - 1;
                GLDS16(nid + (size_t)ar * 128 + kk + chn * 8, Atile + wave * 512);
            }
            int col = wave * 16 + rs;
            GLDS16(Wl1 + (size_t)col * 256 + kk + chn * 8, Btile + wave * 512);
        }
        __syncthreads();
        bf16x8 af;
        if (c8 < 4) {
            af = *(const bf16x8*)(Atile + (g * 16 + m) * 32 + slot * 8);
        } else {
            int row = g * 16 + m;
            af = *(const bf16x8*)(AggXt + row * 128 +
                 (((c8 - 4) * 32 + slot * 8) ^ ((row & 1) << 5)));
        }
#pragma unroll
        for (int t = 0; t < 4; ++t) {
            bf16x8 bfr = *(const bf16x8*)(Btile + (h * 64 + t * 16 + m) * 32 + slot * 8);
            acc[t] = __builtin_amdgcn_mfma_f32_16x16x32_bf16(af, bfr, acc[t], 0, 0, 0);
        }
        __syncthreads();
    }

    // ---- epilogue: relu(HH+l1b) @ l2W, pair-reduce, sigmoid ----
    float bb[4];
#pragma unroll
    for (int t = 0; t < 4; ++t) bb[t] = l1b[h * 64 + t * 16 + m];
    float pr0[4], pr1[4];
#pragma unroll
    for (int r = 0; r < 4; ++r) {
        float p0 = 0.f, p1 = 0.f;
#pragma unroll
        for (int t = 0; t < 4; ++t) {
            int col = h * 64 + t * 16 + m;
            float v = fmaxf(acc[t][r] + bb[t], 0.f);
            p0 = fmaf(v, w2s[col * 2 + 0], p0);
            p1 = fmaf(v, w2s[col * 2 + 1], p1);
        }
#pragma unroll
        for (int mask = 1; mask < 16; mask <<= 1) {
            p0 += __shfl_xor(p0, mask);
            p1 += __shfl_xor(p1, mask);
        }
        pr0[r] = p0; pr1[r] = p1;
    }
    if (h == 1 && m == 0) {
#pragma unroll
        for (int r = 0; r < 4; ++r) {
            int lrow = g * 16 + quad * 4 + r;
            pbuf[lrow][0] = pr0[r];
            pbuf[lrow][1] = pr1[r];
        }
    }
    __syncthreads();
    if (h == 0 && m == 0) {
        float b20 = l2b[0], b21 = l2b[1];
#pragma unroll
        for (int r = 0; r < 4; ++r) {
            int lrow = g * 16 + quad * 4 + r;
            int row = bm + lrow;
            if (row < nrows) {
                float p0 = pr0[r] + pbuf[lrow][0] + b20;
                float p1 = pr1[r] + pbuf[lrow][1] + b21;
                out[(size_t)row * 2 + 0] = 1.f / (1.f + __expf(-p0));
                out[(size_t)row * 2 + 1] = 1.f / (1.f + __expf(-p1));
            }
        }
    }
}

// ---------------------------------------------------------------- launch
extern "C" void kernel_launch(void* const* d_in, const int* in_sizes, int n_in,
                              void* d_out, int out_size, void* d_ws, size_t ws_size,
                              hipStream_t stream)
{
    const float* x    = (const float*)d_in[0];
    const int*   esrc = (const int*)  d_in[1];
    const int*   edst = (const int*)  d_in[2];
    const float* ew   = (const float*)d_in[3];
    const float* preW = (const float*)d_in[4];
    const float* preb = (const float*)d_in[5];
    const float* f1W  = (const float*)d_in[6];
    const float* f1b  = (const float*)d_in[7];
    const float* f2W  = (const float*)d_in[8];
    const float* f2b  = (const float*)d_in[9];
    const float* gW   = (const float*)d_in[10];
    const float* gb   = (const float*)d_in[11];
    const float* fgW  = (const float*)d_in[12];
    const float* fgb  = (const float*)d_in[13];
    const float* l1W  = (const float*)d_in[14];
    const float* l1b  = (const float*)d_in[15];
    const float* l2W  = (const float*)d_in[16];
    const float* l2b  = (const float*)d_in[17];
    float* out = (float*)d_out;

    ushort* wt   = (ushort*)d_ws;
    ushort* wf1  = wt;                          //   4096
    ushort* wf2  = wf1 + 4096;                  //   4096
    ushort* wg   = wf2 + 4096;                  //  98304
    ushort* wfg  = wg  + 98304;                 // 196608
    ushort* wl1  = wfg + 196608;                //  32768
    ushort* h0b  = wl1 + 32768;                 // N*32
    ushort* nidb = h0b  + (size_t)NN * 32;      // N*128
    ushort* hwb  = nidb + (size_t)NN * 128;     // N*128 row-major (ping)
    ushort* hwb2 = hwb  + (size_t)NN * 128;     // N*128 row-major (pong)
    ushort* endu = hwb2 + (size_t)NN * 128;
    unsigned int* esw      = (unsigned int*)(((uintptr_t)endu + 15) & ~(uintptr_t)15);
    unsigned int* stage_pk = esw + NE;
    int*          bcnt     = (int*)(stage_pk + NE);   // NB
    int*          bbase    = bcnt + NB + 1;           // NB+1
    int*          bcur     = bbase + NB + 1;          // NB
    int*          off      = bcur + NB + 1;           // NN+1
    unsigned char* stage_dl = (unsigned char*)(off + NN + 2);  // NE bytes

    const int gblocks = (NN + 63) / 64;         // 782
    const int eblocks = (NE + 1023) / 1024;     // 586

    // ---- CSR build + preproc + weight conversion (merged where independent) ----
    hipMemsetAsync(bcnt, 0, (size_t)NB * sizeof(int), stream);
    convbh_kernel<<<1312 + eblocks, 256, 0, stream>>>(f1W, f2W, gW, fgW, l1W, wt,
                                                      edst, bcnt);
    bscan_kernel<<<1, 512, 0, stream>>>(bcnt, bbase, bcur);
    pass1_kernel<<<eblocks, 256, 0, stream>>>(esrc, edst, ew, bcur, stage_pk, stage_dl);
    p2pre_kernel<<<NB + (NN + 255) / 256, 256, 0, stream>>>(stage_pk, stage_dl, bbase,
                                                            esw, off, x, preW, preb, h0b);

    // ---- network ----
    fc1f0_kernel<<<2 * gblocks, 128, 0, stream>>>(h0b, wf1, f1b, nidb,
                                                  wf2, f2b, wg, hwb);
    ushort* cur = hwb;
    ushort* nxt = hwb2;
    for (int l = 0; l < 5; ++l) {
        gemm_gather<<<gblocks, 512, 0, stream>>>(cur, esw, off,
                                                 gb + (size_t)l * 128, nidb,
                                                 wfg + (size_t)l * 32768,
                                                 fgb + (size_t)l * 128,
                                                 wg + (size_t)(l + 1) * 16384,
                                                 nxt, NN);
        ushort* tmp = cur; cur = nxt; nxt = tmp;
    }
    gemm_last<<<gblocks, 512, 0, stream>>>(cur, esw, off,
                                           gb + (size_t)5 * 128, nidb,
                                           wfg + (size_t)5 * 32768,
                                           fgb + (size_t)5 * 128,
                                           wl1, l1b, l2W, l2b, out, NN);
}